// Round 4
// baseline (3679.124 us; speedup 1.0000x reference)
//
#include <hip/hip_runtime.h>
#include <math.h>

#define BB 4
#define TT 2048
#define HH 12
#define DD 64
#define HID 768
#define RR 512
#define T2 1536
#define TH 1024   // T/2
#define UNM 512   // TH - R
#define SCALEF 0.125f

// ---------------------------------------------------------------------------
// fp32 tiled GEMM: C[M,N] = A[M,K] @ W[K,N] + bias[N] (+ res[M,N] if res!=null)
// 64x64 tile, BK=16, 256 threads, 4x4 per thread. Single accumulator per
// output element, K strictly ascending -> BLAS-like sequential fp32 FMA chain.
// res==C aliasing is safe (each element read then written by one thread).
// ---------------------------------------------------------------------------
__global__ __launch_bounds__(256) void gemm_bias(const float* __restrict__ A,
                                                 const float* __restrict__ Wt,
                                                 const float* __restrict__ bias,
                                                 const float* __restrict__ res,
                                                 float* __restrict__ C,
                                                 int M, int N, int K) {
    __shared__ float As[16][68];   // transposed A tile, padded
    __shared__ float Bs[16][64];
    int tid = threadIdx.x;
    int n0 = blockIdx.x * 64, m0 = blockIdx.y * 64;
    int tx = tid & 15, ty = tid >> 4;
    int la_m = tid >> 2, la_k = (tid & 3) << 2;
    int lb_k = tid >> 4, lb_n = (tid & 15) << 2;
    float acc[4][4] = {};
    for (int k0 = 0; k0 < K; k0 += 16) {
        float4 av = *(const float4*)(A + (size_t)(m0 + la_m) * K + k0 + la_k);
        float4 bv = *(const float4*)(Wt + (size_t)(k0 + lb_k) * N + n0 + lb_n);
        As[la_k + 0][la_m] = av.x; As[la_k + 1][la_m] = av.y;
        As[la_k + 2][la_m] = av.z; As[la_k + 3][la_m] = av.w;
        *(float4*)&Bs[lb_k][lb_n] = bv;
        __syncthreads();
#pragma unroll
        for (int kk = 0; kk < 16; kk++) {
            float4 a = *(const float4*)&As[kk][ty << 2];
            float4 b = *(const float4*)&Bs[kk][tx << 2];
            float ar[4] = {a.x, a.y, a.z, a.w};
            float br[4] = {b.x, b.y, b.z, b.w};
#pragma unroll
            for (int i = 0; i < 4; i++)
#pragma unroll
                for (int j = 0; j < 4; j++) acc[i][j] += ar[i] * br[j];
        }
        __syncthreads();
    }
    float4 bvv = *(const float4*)(bias + n0 + (tx << 2));
#pragma unroll
    for (int i = 0; i < 4; i++) {
        int m = m0 + (ty << 2) + i;
        float4 v;
        v.x = acc[i][0] + bvv.x; v.y = acc[i][1] + bvv.y;
        v.z = acc[i][2] + bvv.z; v.w = acc[i][3] + bvv.w;
        if (res) {
            float4 r = *(const float4*)(res + (size_t)m * N + n0 + (tx << 2));
            v.x += r.x; v.y += r.y; v.z += r.z; v.w += r.w;
        }
        *(float4*)(C + (size_t)m * N + n0 + (tx << 2)) = v;
    }
}

// ---------------------------------------------------------------------------
// metric mean: metric[t,d] = (sum_{h=0..11} k[t, h*64+d]) / 12  (fp32, h asc)
// ---------------------------------------------------------------------------
__global__ __launch_bounds__(256) void metric_mean_kernel(const float* __restrict__ k32,
                                                          float* __restrict__ metric) {
    int idx = blockIdx.x * 256 + threadIdx.x;     // t*64 + d
    if (idx >= BB * TT * DD) return;
    int t = idx >> 6, d = idx & 63;
    float s = 0.f;
#pragma unroll
    for (int h = 0; h < HH; h++) s += k32[(size_t)t * HID + h * DD + d];
    metric[idx] = s / 12.0f;
}

// ---------------------------------------------------------------------------
// metric normalize: one thread per row, sequential fp32 sum of squares.
// ---------------------------------------------------------------------------
__global__ __launch_bounds__(256) void metric_normalize_kernel(float* __restrict__ metric) {
    int row = blockIdx.x * 256 + threadIdx.x;
    if (row >= BB * TT) return;
    float* p = metric + (size_t)row * DD;
    float ss = 0.f;
#pragma unroll
    for (int d = 0; d < DD; d++) ss += p[d] * p[d];
    float denom = sqrtf(ss) + 1e-6f;
#pragma unroll
    for (int d = 0; d < DD; d++) p[d] = p[d] / denom;
}

// ---------------------------------------------------------------------------
// node_max / node_idx (fp32, sequential d chain, first-max tie-break).
// grid (16, B), block 256 (64 i x 4 j-segments).
// ---------------------------------------------------------------------------
__global__ __launch_bounds__(256) void tome_scores_kernel(const float* __restrict__ metric,
                                                          float* __restrict__ node_max,
                                                          int* __restrict__ node_idx) {
    int b = blockIdx.y;
    int i0 = blockIdx.x * 64;
    int tid = threadIdx.x;
    int il = tid & 63, jseg = tid >> 6;
    __shared__ float a_lds[64][65];
    __shared__ float b_lds[64][65];
    __shared__ float mx4[64][4];
    __shared__ int ix4[64][4];
    for (int f = tid; f < 64 * 64; f += 256) {
        int r = f >> 6, c = f & 63;
        a_lds[r][c] = metric[((size_t)b * TT + 2 * (i0 + r)) * DD + c];
    }
    float best = -INFINITY;
    int bidx = 0;
    for (int c0 = 0; c0 < 16; c0++) {
        __syncthreads();
        for (int f = tid; f < 64 * 64; f += 256) {
            int r = f >> 6, c = f & 63;
            b_lds[r][c] = metric[((size_t)b * TT + 2 * (c0 * 64 + r) + 1) * DD + c];
        }
        __syncthreads();
#pragma unroll
        for (int jj = 0; jj < 16; jj++) {
            int jl = jseg + 4 * jj;     // this thread's j's ascend
            float acc = 0.f;
#pragma unroll
            for (int d = 0; d < DD; d++) acc += a_lds[il][d] * b_lds[jl][d];
            int j = c0 * 64 + jl;
            if (acc > best) { best = acc; bidx = j; }   // strict > keeps first max
        }
    }
    mx4[il][jseg] = best;
    ix4[il][jseg] = bidx;
    __syncthreads();
    if (jseg == 0) {
        float bv = mx4[il][0];
        int bi = ix4[il][0];
#pragma unroll
        for (int s2 = 1; s2 < 4; s2++) {
            float v = mx4[il][s2];
            int vi = ix4[il][s2];
            if (v > bv || (v == bv && vi < bi)) { bv = v; bi = vi; }
        }
        node_max[b * TH + i0 + il] = bv;
        node_idx[b * TH + i0 + il] = bi;
    }
}

// ---------------------------------------------------------------------------
// Stable descending argsort via rank counting (fp32 keys, tie -> lower index
// first, matching stable jnp.argsort(-x)). grid B, block 1024.
// ---------------------------------------------------------------------------
__global__ __launch_bounds__(1024) void tome_order_kernel(const float* __restrict__ node_max,
                                                          const int* __restrict__ node_idx,
                                                          int* __restrict__ dst_idx,
                                                          int* __restrict__ src_tok,
                                                          int* __restrict__ unm_tok) {
    __shared__ float vals[TH];
    int b = blockIdx.x;
    int i = threadIdx.x;
    vals[i] = node_max[b * TH + i];
    __syncthreads();
    float v = vals[i];
    int rank = 0;
    for (int j = 0; j < TH; j++) {
        float vj = vals[j];
        rank += (vj > v || (vj == v && j < i)) ? 1 : 0;
    }
    if (rank < RR) {
        src_tok[b * RR + rank] = i;
        dst_idx[b * RR + rank] = node_idx[b * TH + i];
    } else {
        unm_tok[b * UNM + (rank - RR)] = i;
    }
}

__global__ __launch_bounds__(1024) void tome_counts_kernel(const int* __restrict__ dst_idx,
                                                           int* __restrict__ counts) {
    __shared__ int c[TH];
    int b = blockIdx.x;
    int i = threadIdx.x;
    c[i] = 0;
    __syncthreads();
    if (i < RR) atomicAdd(&c[dst_idx[b * RR + i]], 1);
    __syncthreads();
    counts[b * TH + i] = c[i];
}

// ---------------------------------------------------------------------------
// Merge hidden only (merge commutes with affine maps; avg weights sum to 1):
// out rows 0..511 = hidden[2*unm_tok] (rank order), rows 512..1535 = odd rows,
// then scatter-add matched even rows, then scale by 1/(1+count).
// ---------------------------------------------------------------------------
__global__ __launch_bounds__(192) void merge_base_kernel(const float* __restrict__ in,
                                                         float* __restrict__ out,
                                                         const int* __restrict__ unm_tok) {
    int t = blockIdx.x, b = blockIdx.y;
    int src_row = (t < UNM) ? 2 * unm_tok[b * UNM + t] : 2 * (t - UNM) + 1;
    const float4* src = (const float4*)(in + ((size_t)b * TT + src_row) * HID);
    float4* dst = (float4*)(out + ((size_t)b * T2 + t) * HID);
    dst[threadIdx.x] = src[threadIdx.x];
}

__global__ __launch_bounds__(256) void merge_scatter_kernel(const float* __restrict__ in,
                                                            float* __restrict__ out,
                                                            const int* __restrict__ src_tok,
                                                            const int* __restrict__ dst_idx) {
    int s = blockIdx.x, b = blockIdx.y;
    int srow = 2 * src_tok[b * RR + s];
    int drow = UNM + dst_idx[b * RR + s];
    const float* src = in + ((size_t)b * TT + srow) * HID;
    float* dst = out + ((size_t)b * T2 + drow) * HID;
#pragma unroll
    for (int c = threadIdx.x; c < HID; c += 256) atomicAdd(&dst[c], src[c]);
}

__global__ __launch_bounds__(256) void merge_scale_kernel(float* __restrict__ out,
                                                          const int* __restrict__ counts) {
    int r = blockIdx.x, b = blockIdx.y;
    float inv = 1.0f / (1.0f + (float)counts[b * TH + r]);
    float* dst = out + ((size_t)b * T2 + UNM + r) * HID;
#pragma unroll
    for (int c = threadIdx.x; c < HID; c += 256) dst[c] *= inv;
}

// ---------------------------------------------------------------------------
// Flash attention, in-place ctx over qm (each thread reads/writes only its own
// (t, h*64..h*64+63) slice). grid (T2/128, H, B), block 128.
// ---------------------------------------------------------------------------
__global__ __launch_bounds__(128) void attn_kernel(float* __restrict__ qm,
                                                   const float* __restrict__ km,
                                                   const float* __restrict__ vm) {
    int b = blockIdx.z, h = blockIdx.y;
    int t = blockIdx.x * 128 + threadIdx.x;
    float* qp = qm + ((size_t)b * T2 + t) * HID + h * DD;
    float q[DD], o[DD];
#pragma unroll
    for (int d4 = 0; d4 < 16; d4++) {
        float4 v = *(const float4*)(qp + (d4 << 2));
        q[(d4 << 2) + 0] = v.x * SCALEF; q[(d4 << 2) + 1] = v.y * SCALEF;
        q[(d4 << 2) + 2] = v.z * SCALEF; q[(d4 << 2) + 3] = v.w * SCALEF;
    }
#pragma unroll
    for (int d = 0; d < DD; d++) o[d] = 0.f;
    float m = -INFINITY, l = 0.f;
    __shared__ float k_lds[64][DD];
    __shared__ float v_lds[64][DD];
    for (int j0 = 0; j0 < T2; j0 += 64) {
        __syncthreads();
        {
            int f0 = threadIdx.x;
#pragma unroll
            for (int i = 0; i < 8; i++) {
                int f = f0 + i * 128;
                int row = f >> 4, c4 = (f & 15) << 2;
                size_t base = ((size_t)b * T2 + j0 + row) * HID + h * DD + c4;
                *(float4*)&k_lds[row][c4] = *(const float4*)(km + base);
                *(float4*)&v_lds[row][c4] = *(const float4*)(vm + base);
            }
        }
        __syncthreads();
#pragma unroll
        for (int jc = 0; jc < 64; jc += 16) {
            float s[16];
#pragma unroll
            for (int jj = 0; jj < 16; jj++) {
                float acc = 0.f;
#pragma unroll
                for (int d4 = 0; d4 < 16; d4++) {
                    float4 kv = *(const float4*)&k_lds[jc + jj][d4 << 2];
                    acc += q[(d4 << 2)] * kv.x + q[(d4 << 2) + 1] * kv.y +
                           q[(d4 << 2) + 2] * kv.z + q[(d4 << 2) + 3] * kv.w;
                }
                s[jj] = acc;
            }
            float mx = m;
#pragma unroll
            for (int jj = 0; jj < 16; jj++) mx = fmaxf(mx, s[jj]);
            float alpha = __expf(m - mx);
            l *= alpha;
#pragma unroll
            for (int d = 0; d < DD; d++) o[d] *= alpha;
#pragma unroll
            for (int jj = 0; jj < 16; jj++) {
                float pj = __expf(s[jj] - mx);
                l += pj;
#pragma unroll
                for (int d4 = 0; d4 < 16; d4++) {
                    float4 vv = *(const float4*)&v_lds[jc + jj][d4 << 2];
                    o[(d4 << 2) + 0] += pj * vv.x; o[(d4 << 2) + 1] += pj * vv.y;
                    o[(d4 << 2) + 2] += pj * vv.z; o[(d4 << 2) + 3] += pj * vv.w;
                }
            }
            m = mx;
        }
    }
    float inv = 1.f / l;
#pragma unroll
    for (int d4 = 0; d4 < 16; d4++) {
        float4 v;
        v.x = o[(d4 << 2) + 0] * inv; v.y = o[(d4 << 2) + 1] * inv;
        v.z = o[(d4 << 2) + 2] * inv; v.w = o[(d4 << 2) + 3] * inv;
        *(float4*)(qp + (d4 << 2)) = v;
    }
}

// ---------------------------------------------------------------------------
// LayerNorm in place: grid B*T2 rows, block 256 (each thread 3 cols)
// ---------------------------------------------------------------------------
__global__ __launch_bounds__(256) void ln_kernel(float* __restrict__ out,
                                                 const float* __restrict__ gamma,
                                                 const float* __restrict__ beta) {
    int row = blockIdx.x;
    int tid = threadIdx.x;
    float* p = out + (size_t)row * HID;
    float x[3];
#pragma unroll
    for (int i = 0; i < 3; i++) x[i] = p[tid + i * 256];
    float s = x[0] + x[1] + x[2];
#pragma unroll
    for (int off = 1; off < 64; off <<= 1) s += __shfl_xor(s, off);
    __shared__ float sb[4];
    int wid = tid >> 6;
    if ((tid & 63) == 0) sb[wid] = s;
    __syncthreads();
    float mu = (sb[0] + sb[1] + sb[2] + sb[3]) * (1.0f / HID);
    float vs = 0.f;
#pragma unroll
    for (int i = 0; i < 3; i++) {
        float d = x[i] - mu;
        vs += d * d;
    }
#pragma unroll
    for (int off = 1; off < 64; off <<= 1) vs += __shfl_xor(vs, off);
    __syncthreads();
    if ((tid & 63) == 0) sb[wid] = vs;
    __syncthreads();
    float var = (sb[0] + sb[1] + sb[2] + sb[3]) * (1.0f / HID);
    float inv = rsqrtf(var + 1e-12f);
#pragma unroll
    for (int i = 0; i < 3; i++) {
        int c = tid + i * 256;
        p[c] = (x[i] - mu) * inv * gamma[c] + beta[c];
    }
}

// ---------------------------------------------------------------------------
// Workspace: qm/km/vm 3*18.87MB = 56.6MB; k32 (25.2MB) OVERLAPS [qm..qm+25.2MB)
// and is dead before qm/km are written; metric fp32 2.1MB + index buffers.
// Total ~59MB. Residual rm lives in d_out (element-wise-safe aliasing).
// ---------------------------------------------------------------------------
extern "C" void kernel_launch(void* const* d_in, const int* in_sizes, int n_in,
                              void* d_out, int out_size, void* d_ws, size_t ws_size,
                              hipStream_t stream) {
    const float* hidden = (const float*)d_in[0];
    const float* Wq = (const float*)d_in[1];
    const float* bq = (const float*)d_in[2];
    const float* Wk = (const float*)d_in[3];
    const float* bk = (const float*)d_in[4];
    const float* Wv = (const float*)d_in[5];
    const float* bv = (const float*)d_in[6];
    const float* Wo = (const float*)d_in[7];
    const float* bo = (const float*)d_in[8];
    const float* gamma = (const float*)d_in[9];
    const float* beta = (const float*)d_in[10];

    float* ws = (float*)d_ws;
    const size_t SZ_MERG = (size_t)BB * T2 * HID;   // 4718592 floats
    float* qm = ws;
    float* km = qm + SZ_MERG;
    float* vm = km + SZ_MERG;
    float* k32 = qm;                                 // overlap; dead before step 7
    float* metric = vm + SZ_MERG;                    // B*T*64 fp32
    float* node_max = metric + (size_t)BB * TT * DD; // B*1024 fp32
    int* node_idx = (int*)(node_max + BB * TH);      // B*1024
    int* dst_idx = node_idx + BB * TH;               // B*512
    int* src_tok = dst_idx + BB * RR;                // B*512
    int* unm_tok = src_tok + BB * RR;                // B*512
    int* counts = unm_tok + BB * UNM;                // B*1024
    float* rm = (float*)d_out;                       // merged residual in d_out

    // 1. full k = hidden @ Wk + bk (fp32, sequential-K chain like BLAS)
    gemm_bias<<<dim3(HID / 64, BB * TT / 64), 256, 0, stream>>>(hidden, Wk, bk, nullptr, k32, BB * TT, HID, HID);

    // 2. metric = head-mean of k (fp32, h ascending, /12)
    metric_mean_kernel<<<(BB * TT * DD + 255) / 256, 256, 0, stream>>>(k32, metric);

    // 3. normalize metric rows (fp32, sequential per row)
    metric_normalize_kernel<<<(BB * TT + 255) / 256, 256, 0, stream>>>(metric);

    // 4. scores -> node_max / node_idx (fp32)
    tome_scores_kernel<<<dim3(16, BB), 256, 0, stream>>>(metric, node_max, node_idx);

    // 5. stable descending order -> src/unm/dst
    tome_order_kernel<<<BB, 1024, 0, stream>>>(node_max, node_idx, dst_idx, src_tok, unm_tok);

    // 6. counts
    tome_counts_kernel<<<BB, 1024, 0, stream>>>(dst_idx, counts);

    // 7. merge hidden -> rm (residual, in d_out)
    merge_base_kernel<<<dim3(T2, BB), 192, 0, stream>>>(hidden, rm, unm_tok);
    merge_scatter_kernel<<<dim3(RR, BB), 256, 0, stream>>>(hidden, rm, src_tok, dst_idx);
    merge_scale_kernel<<<dim3(TH, BB), 256, 0, stream>>>(rm, counts);

    // 8. QKV projections at T2 (merge commutes with affine maps)
    gemm_bias<<<dim3(HID / 64, BB * T2 / 64), 256, 0, stream>>>(rm, Wq, bq, nullptr, qm, BB * T2, HID, HID);
    gemm_bias<<<dim3(HID / 64, BB * T2 / 64), 256, 0, stream>>>(rm, Wk, bk, nullptr, km, BB * T2, HID, HID);
    gemm_bias<<<dim3(HID / 64, BB * T2 / 64), 256, 0, stream>>>(rm, Wv, bv, nullptr, vm, BB * T2, HID, HID);

    // 9. attention, ctx in-place over qm
    attn_kernel<<<dim3(T2 / 128, HH, BB), 128, 0, stream>>>(qm, km, vm);

    // 10. out = ctx @ Wo + bo + residual (res aliases C element-wise safely)
    gemm_bias<<<dim3(HID / 64, BB * T2 / 64), 256, 0, stream>>>(qm, Wo, bo, rm, (float*)d_out, BB * T2, HID, HID);

    // 11. LayerNorm in place
    ln_kernel<<<BB * T2, 256, 0, stream>>>((float*)d_out, gamma, beta);
}

// Round 5
// 1210.238 us; speedup vs baseline: 3.0400x; 3.0400x over previous
//
#include <hip/hip_runtime.h>
#include <math.h>

#define BB 4
#define TT 2048
#define HH 12
#define DD 64
#define HID 768
#define RR 512
#define T2 1536
#define TH 1024   // T/2
#define UNM 512   // TH - R
#define SCALEF 0.125f

typedef short bf8v __attribute__((ext_vector_type(8)));
typedef float f4v  __attribute__((ext_vector_type(4)));

// float -> bf16 round-to-nearest-even
__device__ inline short f2bf(float f) {
    unsigned u = __float_as_uint(f);
    u += 0x7fffu + ((u >> 16) & 1u);
    return (short)(u >> 16);
}

// ---------------------------------------------------------------------------
// fp32 tiled GEMM: C[M,N] = A[M,K] @ W[K,N] + bias[N] (+ res[M,N] if res!=null)
// 64x64 tile, BK=16, 256 threads, 4x4 per thread. Single accumulator per
// output element, K strictly ascending -> BLAS-like sequential fp32 FMA chain.
// res==C aliasing is safe (each element read then written by one thread).
// ---------------------------------------------------------------------------
__global__ __launch_bounds__(256) void gemm_bias(const float* __restrict__ A,
                                                 const float* __restrict__ Wt,
                                                 const float* __restrict__ bias,
                                                 const float* __restrict__ res,
                                                 float* __restrict__ C,
                                                 int M, int N, int K) {
    __shared__ float As[16][68];   // transposed A tile, padded
    __shared__ float Bs[16][64];
    int tid = threadIdx.x;
    int n0 = blockIdx.x * 64, m0 = blockIdx.y * 64;
    int tx = tid & 15, ty = tid >> 4;
    int la_m = tid >> 2, la_k = (tid & 3) << 2;
    int lb_k = tid >> 4, lb_n = (tid & 15) << 2;
    float acc[4][4] = {};
    for (int k0 = 0; k0 < K; k0 += 16) {
        float4 av = *(const float4*)(A + (size_t)(m0 + la_m) * K + k0 + la_k);
        float4 bv = *(const float4*)(Wt + (size_t)(k0 + lb_k) * N + n0 + lb_n);
        As[la_k + 0][la_m] = av.x; As[la_k + 1][la_m] = av.y;
        As[la_k + 2][la_m] = av.z; As[la_k + 3][la_m] = av.w;
        *(float4*)&Bs[lb_k][lb_n] = bv;
        __syncthreads();
#pragma unroll
        for (int kk = 0; kk < 16; kk++) {
            float4 a = *(const float4*)&As[kk][ty << 2];
            float4 b = *(const float4*)&Bs[kk][tx << 2];
            float ar[4] = {a.x, a.y, a.z, a.w};
            float br[4] = {b.x, b.y, b.z, b.w};
#pragma unroll
            for (int i = 0; i < 4; i++)
#pragma unroll
                for (int j = 0; j < 4; j++) acc[i][j] += ar[i] * br[j];
        }
        __syncthreads();
    }
    float4 bvv = *(const float4*)(bias + n0 + (tx << 2));
#pragma unroll
    for (int i = 0; i < 4; i++) {
        int m = m0 + (ty << 2) + i;
        float4 v;
        v.x = acc[i][0] + bvv.x; v.y = acc[i][1] + bvv.y;
        v.z = acc[i][2] + bvv.z; v.w = acc[i][3] + bvv.w;
        if (res) {
            float4 r = *(const float4*)(res + (size_t)m * N + n0 + (tx << 2));
            v.x += r.x; v.y += r.y; v.z += r.z; v.w += r.w;
        }
        *(float4*)(C + (size_t)m * N + n0 + (tx << 2)) = v;
    }
}

// ---------------------------------------------------------------------------
// metric mean: metric[t,d] = (sum_{h=0..11} k[t, h*64+d]) / 12  (fp32, h asc)
// ---------------------------------------------------------------------------
__global__ __launch_bounds__(256) void metric_mean_kernel(const float* __restrict__ k32,
                                                          float* __restrict__ metric) {
    int idx = blockIdx.x * 256 + threadIdx.x;     // t*64 + d
    if (idx >= BB * TT * DD) return;
    int t = idx >> 6, d = idx & 63;
    float s = 0.f;
#pragma unroll
    for (int h = 0; h < HH; h++) s += k32[(size_t)t * HID + h * DD + d];
    metric[idx] = s / 12.0f;
}

// ---------------------------------------------------------------------------
// metric normalize: one thread per row, sequential fp32 sum of squares.
// ---------------------------------------------------------------------------
__global__ __launch_bounds__(256) void metric_normalize_kernel(float* __restrict__ metric) {
    int row = blockIdx.x * 256 + threadIdx.x;
    if (row >= BB * TT) return;
    float* p = metric + (size_t)row * DD;
    float ss = 0.f;
#pragma unroll
    for (int d = 0; d < DD; d++) ss += p[d] * p[d];
    float denom = sqrtf(ss) + 1e-6f;
#pragma unroll
    for (int d = 0; d < DD; d++) p[d] = p[d] / denom;
}

// ---------------------------------------------------------------------------
// node_max / node_idx (fp32, sequential d chain, first-max tie-break).
// grid (16, B), block 256 (64 i x 4 j-segments).
// ---------------------------------------------------------------------------
__global__ __launch_bounds__(256) void tome_scores_kernel(const float* __restrict__ metric,
                                                          float* __restrict__ node_max,
                                                          int* __restrict__ node_idx) {
    int b = blockIdx.y;
    int i0 = blockIdx.x * 64;
    int tid = threadIdx.x;
    int il = tid & 63, jseg = tid >> 6;
    __shared__ float a_lds[64][65];
    __shared__ float b_lds[64][65];
    __shared__ float mx4[64][4];
    __shared__ int ix4[64][4];
    for (int f = tid; f < 64 * 64; f += 256) {
        int r = f >> 6, c = f & 63;
        a_lds[r][c] = metric[((size_t)b * TT + 2 * (i0 + r)) * DD + c];
    }
    float best = -INFINITY;
    int bidx = 0;
    for (int c0 = 0; c0 < 16; c0++) {
        __syncthreads();
        for (int f = tid; f < 64 * 64; f += 256) {
            int r = f >> 6, c = f & 63;
            b_lds[r][c] = metric[((size_t)b * TT + 2 * (c0 * 64 + r) + 1) * DD + c];
        }
        __syncthreads();
#pragma unroll
        for (int jj = 0; jj < 16; jj++) {
            int jl = jseg + 4 * jj;     // this thread's j's ascend
            float acc = 0.f;
#pragma unroll
            for (int d = 0; d < DD; d++) acc += a_lds[il][d] * b_lds[jl][d];
            int j = c0 * 64 + jl;
            if (acc > best) { best = acc; bidx = j; }   // strict > keeps first max
        }
    }
    mx4[il][jseg] = best;
    ix4[il][jseg] = bidx;
    __syncthreads();
    if (jseg == 0) {
        float bv = mx4[il][0];
        int bi = ix4[il][0];
#pragma unroll
        for (int s2 = 1; s2 < 4; s2++) {
            float v = mx4[il][s2];
            int vi = ix4[il][s2];
            if (v > bv || (v == bv && vi < bi)) { bv = v; bi = vi; }
        }
        node_max[b * TH + i0 + il] = bv;
        node_idx[b * TH + i0 + il] = bi;
    }
}

// ---------------------------------------------------------------------------
// Stable descending argsort via rank counting (fp32 keys, tie -> lower index
// first, matching stable jnp.argsort(-x)). grid B, block 1024.
// ---------------------------------------------------------------------------
__global__ __launch_bounds__(1024) void tome_order_kernel(const float* __restrict__ node_max,
                                                          const int* __restrict__ node_idx,
                                                          int* __restrict__ dst_idx,
                                                          int* __restrict__ src_tok,
                                                          int* __restrict__ unm_tok) {
    __shared__ float vals[TH];
    int b = blockIdx.x;
    int i = threadIdx.x;
    vals[i] = node_max[b * TH + i];
    __syncthreads();
    float v = vals[i];
    int rank = 0;
    for (int j = 0; j < TH; j++) {
        float vj = vals[j];
        rank += (vj > v || (vj == v && j < i)) ? 1 : 0;
    }
    if (rank < RR) {
        src_tok[b * RR + rank] = i;
        dst_idx[b * RR + rank] = node_idx[b * TH + i];
    } else {
        unm_tok[b * UNM + (rank - RR)] = i;
    }
}

__global__ __launch_bounds__(1024) void tome_counts_kernel(const int* __restrict__ dst_idx,
                                                           int* __restrict__ counts) {
    __shared__ int c[TH];
    int b = blockIdx.x;
    int i = threadIdx.x;
    c[i] = 0;
    __syncthreads();
    if (i < RR) atomicAdd(&c[dst_idx[b * RR + i]], 1);
    __syncthreads();
    counts[b * TH + i] = c[i];
}

// ---------------------------------------------------------------------------
// Merge hidden only (merge commutes with affine maps; avg weights sum to 1).
// ---------------------------------------------------------------------------
__global__ __launch_bounds__(192) void merge_base_kernel(const float* __restrict__ in,
                                                         float* __restrict__ out,
                                                         const int* __restrict__ unm_tok) {
    int t = blockIdx.x, b = blockIdx.y;
    int src_row = (t < UNM) ? 2 * unm_tok[b * UNM + t] : 2 * (t - UNM) + 1;
    const float4* src = (const float4*)(in + ((size_t)b * TT + src_row) * HID);
    float4* dst = (float4*)(out + ((size_t)b * T2 + t) * HID);
    dst[threadIdx.x] = src[threadIdx.x];
}

__global__ __launch_bounds__(256) void merge_scatter_kernel(const float* __restrict__ in,
                                                            float* __restrict__ out,
                                                            const int* __restrict__ src_tok,
                                                            const int* __restrict__ dst_idx) {
    int s = blockIdx.x, b = blockIdx.y;
    int srow = 2 * src_tok[b * RR + s];
    int drow = UNM + dst_idx[b * RR + s];
    const float* src = in + ((size_t)b * TT + srow) * HID;
    float* dst = out + ((size_t)b * T2 + drow) * HID;
#pragma unroll
    for (int c = threadIdx.x; c < HID; c += 256) atomicAdd(&dst[c], src[c]);
}

__global__ __launch_bounds__(256) void merge_scale_kernel(float* __restrict__ out,
                                                          const int* __restrict__ counts) {
    int r = blockIdx.x, b = blockIdx.y;
    float inv = 1.0f / (1.0f + (float)counts[b * TH + r]);
    float* dst = out + ((size_t)b * T2 + UNM + r) * HID;
#pragma unroll
    for (int c = threadIdx.x; c < HID; c += 256) dst[c] *= inv;
}

// ---------------------------------------------------------------------------
// MFMA bf16 flash attention. Block = 256 threads = 4 waves; block handles
// 64 q rows of one (b,h); each wave owns 16 q rows. K-chunk = 64 rows.
// Q/P are A-frags (A[m=lane&15][k=quad*8+i]); K row-major and V transposed
// in LDS give contiguous 16B B-frag reads (B[k][n=lane&15]).
// S/O live in C-layout (col=lane&15, row=quad*4+reg). fp32 accumulate.
// In-place: writes only its own (rows, head-cols) slice of qm.
// ---------------------------------------------------------------------------
__global__ __launch_bounds__(256) void attn_mfma_kernel(float* __restrict__ qm,
                                                        const float* __restrict__ km,
                                                        const float* __restrict__ vm) {
    __shared__ short Ks[64][72];    // K chunk, row-major (j, d), stride 144B
    __shared__ short Vts[64][72];   // V chunk, transposed (d, j)
    __shared__ short Ps[4][16][72]; // per-wave P (16 q rows x 64 j)

    const int b = blockIdx.z, h = blockIdx.y;
    const int tid = threadIdx.x;
    const int w = tid >> 6;          // wave 0..3
    const int lane = tid & 63;
    const int quad = lane >> 4;      // 0..3
    const int l = lane & 15;         // 0..15
    const int q0 = blockIdx.x * 64 + w * 16;   // wave's first q row

    // ---- load Q fragments (A-layout), scaled by 1/8 ----
    bf8v aq0, aq1;
    {
        const float* qp = qm + ((size_t)b * T2 + q0 + l) * HID + h * DD;
        float4 x0 = *(const float4*)(qp + quad * 8);
        float4 x1 = *(const float4*)(qp + quad * 8 + 4);
        float4 x2 = *(const float4*)(qp + 32 + quad * 8);
        float4 x3 = *(const float4*)(qp + 32 + quad * 8 + 4);
        aq0[0] = f2bf(x0.x * SCALEF); aq0[1] = f2bf(x0.y * SCALEF);
        aq0[2] = f2bf(x0.z * SCALEF); aq0[3] = f2bf(x0.w * SCALEF);
        aq0[4] = f2bf(x1.x * SCALEF); aq0[5] = f2bf(x1.y * SCALEF);
        aq0[6] = f2bf(x1.z * SCALEF); aq0[7] = f2bf(x1.w * SCALEF);
        aq1[0] = f2bf(x2.x * SCALEF); aq1[1] = f2bf(x2.y * SCALEF);
        aq1[2] = f2bf(x2.z * SCALEF); aq1[3] = f2bf(x2.w * SCALEF);
        aq1[4] = f2bf(x3.x * SCALEF); aq1[5] = f2bf(x3.y * SCALEF);
        aq1[6] = f2bf(x3.z * SCALEF); aq1[7] = f2bf(x3.w * SCALEF);
    }

    f4v O[4];
#pragma unroll
    for (int t = 0; t < 4; t++) O[t] = (f4v){0.f, 0.f, 0.f, 0.f};
    float mrow[4] = {-INFINITY, -INFINITY, -INFINITY, -INFINITY};
    float lrow[4] = {0.f, 0.f, 0.f, 0.f};

    // staging coords: thread handles 4x4 block (rows j0..j0+3, cols d0..d0+3)
    const int j0s = (tid & 15) << 2;
    const int d0s = (tid >> 4) << 2;

    for (int c0 = 0; c0 < T2; c0 += 64) {
        __syncthreads();
        // ---- stage K (row-major) and V (transposed) as bf16 ----
        {
            float4 kr[4], vr[4];
#pragma unroll
            for (int jj = 0; jj < 4; jj++) {
                size_t base = ((size_t)b * T2 + c0 + j0s + jj) * HID + h * DD + d0s;
                kr[jj] = *(const float4*)(km + base);
                vr[jj] = *(const float4*)(vm + base);
            }
#pragma unroll
            for (int jj = 0; jj < 4; jj++) {
                short4 kk;
                kk.x = f2bf(kr[jj].x); kk.y = f2bf(kr[jj].y);
                kk.z = f2bf(kr[jj].z); kk.w = f2bf(kr[jj].w);
                *(short4*)&Ks[j0s + jj][d0s] = kk;
            }
            {
                short4 t0, t1, t2, t3;
                t0.x = f2bf(vr[0].x); t0.y = f2bf(vr[1].x); t0.z = f2bf(vr[2].x); t0.w = f2bf(vr[3].x);
                t1.x = f2bf(vr[0].y); t1.y = f2bf(vr[1].y); t1.z = f2bf(vr[2].y); t1.w = f2bf(vr[3].y);
                t2.x = f2bf(vr[0].z); t2.y = f2bf(vr[1].z); t2.z = f2bf(vr[2].z); t2.w = f2bf(vr[3].z);
                t3.x = f2bf(vr[0].w); t3.y = f2bf(vr[1].w); t3.z = f2bf(vr[2].w); t3.w = f2bf(vr[3].w);
                *(short4*)&Vts[d0s + 0][j0s] = t0;
                *(short4*)&Vts[d0s + 1][j0s] = t1;
                *(short4*)&Vts[d0s + 2][j0s] = t2;
                *(short4*)&Vts[d0s + 3][j0s] = t3;
            }
        }
        __syncthreads();

        // ---- S = Q K^T (4 j-tiles of 16) ----
        f4v s[4];
#pragma unroll
        for (int t = 0; t < 4; t++) {
            bf8v bk0 = *(const bf8v*)&Ks[t * 16 + l][quad * 8];
            bf8v bk1 = *(const bf8v*)&Ks[t * 16 + l][32 + quad * 8];
            f4v acc = (f4v){0.f, 0.f, 0.f, 0.f};
            acc = __builtin_amdgcn_mfma_f32_16x16x32_bf16(aq0, bk0, acc, 0, 0, 0);
            acc = __builtin_amdgcn_mfma_f32_16x16x32_bf16(aq1, bk1, acc, 0, 0, 0);
            s[t] = acc;
        }

        // ---- online softmax over this chunk ----
        float rmax[4], alpha[4], rsum[4];
#pragma unroll
        for (int r = 0; r < 4; r++) {
            float mx = s[0][r];
            mx = fmaxf(mx, s[1][r]); mx = fmaxf(mx, s[2][r]); mx = fmaxf(mx, s[3][r]);
            rmax[r] = mx;
        }
#pragma unroll
        for (int off = 1; off < 16; off <<= 1) {
#pragma unroll
            for (int r = 0; r < 4; r++) rmax[r] = fmaxf(rmax[r], __shfl_xor(rmax[r], off));
        }
        float p[4][4];
#pragma unroll
        for (int r = 0; r < 4; r++) {
            float mnew = fmaxf(mrow[r], rmax[r]);
            alpha[r] = __expf(mrow[r] - mnew);
            mrow[r] = mnew;
            float ps = 0.f;
#pragma unroll
            for (int t = 0; t < 4; t++) {
                float pv = __expf(s[t][r] - mnew);
                p[t][r] = pv;
                ps += pv;
            }
            rsum[r] = ps;
        }
#pragma unroll
        for (int off = 1; off < 16; off <<= 1) {
#pragma unroll
            for (int r = 0; r < 4; r++) rsum[r] += __shfl_xor(rsum[r], off);
        }
#pragma unroll
        for (int r = 0; r < 4; r++) lrow[r] = lrow[r] * alpha[r] + rsum[r];
        // rescale O
#pragma unroll
        for (int t = 0; t < 4; t++)
#pragma unroll
            for (int r = 0; r < 4; r++) O[t][r] *= alpha[r];

        // ---- P to LDS (C-layout -> A-layout round trip) ----
#pragma unroll
        for (int t = 0; t < 4; t++)
#pragma unroll
            for (int r = 0; r < 4; r++)
                Ps[w][quad * 4 + r][t * 16 + l] = f2bf(p[t][r]);

        // ---- O += P V ----
        {
            bf8v ap0 = *(const bf8v*)&Ps[w][l][quad * 8];
            bf8v ap1 = *(const bf8v*)&Ps[w][l][32 + quad * 8];
#pragma unroll
            for (int t = 0; t < 4; t++) {
                bf8v bv0 = *(const bf8v*)&Vts[t * 16 + l][quad * 8];
                bf8v bv1 = *(const bf8v*)&Vts[t * 16 + l][32 + quad * 8];
                O[t] = __builtin_amdgcn_mfma_f32_16x16x32_bf16(ap0, bv0, O[t], 0, 0, 0);
                O[t] = __builtin_amdgcn_mfma_f32_16x16x32_bf16(ap1, bv1, O[t], 0, 0, 0);
            }
        }
    }

    // ---- normalize and write ctx in place of q ----
    float inv[4];
#pragma unroll
    for (int r = 0; r < 4; r++) inv[r] = 1.0f / lrow[r];
#pragma unroll
    for (int r = 0; r < 4; r++) {
        float* op = qm + ((size_t)b * T2 + q0 + quad * 4 + r) * HID + h * DD;
#pragma unroll
        for (int t = 0; t < 4; t++) op[t * 16 + l] = O[t][r] * inv[r];
    }
}

// ---------------------------------------------------------------------------
// LayerNorm in place: grid B*T2 rows, block 256 (each thread 3 cols)
// ---------------------------------------------------------------------------
__global__ __launch_bounds__(256) void ln_kernel(float* __restrict__ out,
                                                 const float* __restrict__ gamma,
                                                 const float* __restrict__ beta) {
    int row = blockIdx.x;
    int tid = threadIdx.x;
    float* p = out + (size_t)row * HID;
    float x[3];
#pragma unroll
    for (int i = 0; i < 3; i++) x[i] = p[tid + i * 256];
    float s = x[0] + x[1] + x[2];
#pragma unroll
    for (int off = 1; off < 64; off <<= 1) s += __shfl_xor(s, off);
    __shared__ float sb[4];
    int wid = tid >> 6;
    if ((tid & 63) == 0) sb[wid] = s;
    __syncthreads();
    float mu = (sb[0] + sb[1] + sb[2] + sb[3]) * (1.0f / HID);
    float vs = 0.f;
#pragma unroll
    for (int i = 0; i < 3; i++) {
        float d = x[i] - mu;
        vs += d * d;
    }
#pragma unroll
    for (int off = 1; off < 64; off <<= 1) vs += __shfl_xor(vs, off);
    __syncthreads();
    if ((tid & 63) == 0) sb[wid] = vs;
    __syncthreads();
    float var = (sb[0] + sb[1] + sb[2] + sb[3]) * (1.0f / HID);
    float inv = rsqrtf(var + 1e-12f);
#pragma unroll
    for (int i = 0; i < 3; i++) {
        int c = tid + i * 256;
        p[c] = (x[i] - mu) * inv * gamma[c] + beta[c];
    }
}

// ---------------------------------------------------------------------------
extern "C" void kernel_launch(void* const* d_in, const int* in_sizes, int n_in,
                              void* d_out, int out_size, void* d_ws, size_t ws_size,
                              hipStream_t stream) {
    const float* hidden = (const float*)d_in[0];
    const float* Wq = (const float*)d_in[1];
    const float* bq = (const float*)d_in[2];
    const float* Wk = (const float*)d_in[3];
    const float* bk = (const float*)d_in[4];
    const float* Wv = (const float*)d_in[5];
    const float* bv = (const float*)d_in[6];
    const float* Wo = (const float*)d_in[7];
    const float* bo = (const float*)d_in[8];
    const float* gamma = (const float*)d_in[9];
    const float* beta = (const float*)d_in[10];

    float* ws = (float*)d_ws;
    const size_t SZ_MERG = (size_t)BB * T2 * HID;   // 4718592 floats
    float* qm = ws;
    float* km = qm + SZ_MERG;
    float* vm = km + SZ_MERG;
    float* k32 = qm;                                 // overlap; dead before step 8
    float* metric = vm + SZ_MERG;                    // B*T*64 fp32
    float* node_max = metric + (size_t)BB * TT * DD; // B*1024 fp32
    int* node_idx = (int*)(node_max + BB * TH);      // B*1024
    int* dst_idx = node_idx + BB * TH;               // B*512
    int* src_tok = dst_idx + BB * RR;                // B*512
    int* unm_tok = src_tok + BB * RR;                // B*512
    int* counts = unm_tok + BB * UNM;                // B*1024
    float* rm = (float*)d_out;                       // merged residual in d_out

    // 1. full k = hidden @ Wk + bk (fp32, sequential-K chain like BLAS)
    gemm_bias<<<dim3(HID / 64, BB * TT / 64), 256, 0, stream>>>(hidden, Wk, bk, nullptr, k32, BB * TT, HID, HID);

    // 2. metric = head-mean of k (fp32, h ascending, /12)
    metric_mean_kernel<<<(BB * TT * DD + 255) / 256, 256, 0, stream>>>(k32, metric);

    // 3. normalize metric rows (fp32, sequential per row)
    metric_normalize_kernel<<<(BB * TT + 255) / 256, 256, 0, stream>>>(metric);

    // 4. scores -> node_max / node_idx (fp32)
    tome_scores_kernel<<<dim3(16, BB), 256, 0, stream>>>(metric, node_max, node_idx);

    // 5. stable descending order -> src/unm/dst
    tome_order_kernel<<<BB, 1024, 0, stream>>>(node_max, node_idx, dst_idx, src_tok, unm_tok);

    // 6. counts
    tome_counts_kernel<<<BB, 1024, 0, stream>>>(dst_idx, counts);

    // 7. merge hidden -> rm (residual, in d_out)
    merge_base_kernel<<<dim3(T2, BB), 192, 0, stream>>>(hidden, rm, unm_tok);
    merge_scatter_kernel<<<dim3(RR, BB), 256, 0, stream>>>(hidden, rm, src_tok, dst_idx);
    merge_scale_kernel<<<dim3(TH, BB), 256, 0, stream>>>(rm, counts);

    // 8. QKV projections at T2 (merge commutes with affine maps)
    gemm_bias<<<dim3(HID / 64, BB * T2 / 64), 256, 0, stream>>>(rm, Wq, bq, nullptr, qm, BB * T2, HID, HID);
    gemm_bias<<<dim3(HID / 64, BB * T2 / 64), 256, 0, stream>>>(rm, Wk, bk, nullptr, km, BB * T2, HID, HID);
    gemm_bias<<<dim3(HID / 64, BB * T2 / 64), 256, 0, stream>>>(rm, Wv, bv, nullptr, vm, BB * T2, HID, HID);

    // 9. MFMA flash attention, ctx in-place over qm
    attn_mfma_kernel<<<dim3(T2 / 64, HH, BB), 256, 0, stream>>>(qm, km, vm);

    // 10. out = ctx @ Wo + bo + residual (res aliases C element-wise safely)
    gemm_bias<<<dim3(HID / 64, BB * T2 / 64), 256, 0, stream>>>(qm, Wo, bo, rm, (float*)d_out, BB * T2, HID, HID);

    // 11. LayerNorm in place
    ln_kernel<<<BB * T2, 256, 0, stream>>>((float*)d_out, gamma, beta);
}

// Round 6
// 952.168 us; speedup vs baseline: 3.8639x; 1.2710x over previous
//
#include <hip/hip_runtime.h>
#include <math.h>

#define BB 4
#define TT 2048
#define HH 12
#define DD 64
#define HID 768
#define RR 512
#define T2 1536
#define TH 1024   // T/2
#define UNM 512   // TH - R
#define SCALEF 0.125f

typedef short bf8v __attribute__((ext_vector_type(8)));
typedef float f4v  __attribute__((ext_vector_type(4)));

// float -> bf16 round-to-nearest-even
__device__ inline short f2bf(float f) {
    unsigned u = __float_as_uint(f);
    u += 0x7fffu + ((u >> 16) & 1u);
    return (short)(u >> 16);
}

// ---------------------------------------------------------------------------
// fp32 tiled GEMM: C[M,N] = A[M,K] @ W[K,N] + bias[N] (+ res[M,N] if res!=null)
// 64x64 tile, BK=16, 256 threads, 4x4 per thread. Single accumulator per
// output element, K strictly ascending -> BLAS-like sequential fp32 FMA chain.
// res==C aliasing is safe (each element read then written by one thread).
// ---------------------------------------------------------------------------
__global__ __launch_bounds__(256) void gemm_bias(const float* __restrict__ A,
                                                 const float* __restrict__ Wt,
                                                 const float* __restrict__ bias,
                                                 const float* __restrict__ res,
                                                 float* __restrict__ C,
                                                 int M, int N, int K) {
    __shared__ float As[16][68];   // transposed A tile, padded
    __shared__ float Bs[16][64];
    int tid = threadIdx.x;
    int n0 = blockIdx.x * 64, m0 = blockIdx.y * 64;
    int tx = tid & 15, ty = tid >> 4;
    int la_m = tid >> 2, la_k = (tid & 3) << 2;
    int lb_k = tid >> 4, lb_n = (tid & 15) << 2;
    float acc[4][4] = {};
    for (int k0 = 0; k0 < K; k0 += 16) {
        float4 av = *(const float4*)(A + (size_t)(m0 + la_m) * K + k0 + la_k);
        float4 bv = *(const float4*)(Wt + (size_t)(k0 + lb_k) * N + n0 + lb_n);
        As[la_k + 0][la_m] = av.x; As[la_k + 1][la_m] = av.y;
        As[la_k + 2][la_m] = av.z; As[la_k + 3][la_m] = av.w;
        *(float4*)&Bs[lb_k][lb_n] = bv;
        __syncthreads();
#pragma unroll
        for (int kk = 0; kk < 16; kk++) {
            float4 a = *(const float4*)&As[kk][ty << 2];
            float4 b = *(const float4*)&Bs[kk][tx << 2];
            float ar[4] = {a.x, a.y, a.z, a.w};
            float br[4] = {b.x, b.y, b.z, b.w};
#pragma unroll
            for (int i = 0; i < 4; i++)
#pragma unroll
                for (int j = 0; j < 4; j++) acc[i][j] += ar[i] * br[j];
        }
        __syncthreads();
    }
    float4 bvv = *(const float4*)(bias + n0 + (tx << 2));
#pragma unroll
    for (int i = 0; i < 4; i++) {
        int m = m0 + (ty << 2) + i;
        float4 v;
        v.x = acc[i][0] + bvv.x; v.y = acc[i][1] + bvv.y;
        v.z = acc[i][2] + bvv.z; v.w = acc[i][3] + bvv.w;
        if (res) {
            float4 r = *(const float4*)(res + (size_t)m * N + n0 + (tx << 2));
            v.x += r.x; v.y += r.y; v.z += r.z; v.w += r.w;
        }
        *(float4*)(C + (size_t)m * N + n0 + (tx << 2)) = v;
    }
}

// ---------------------------------------------------------------------------
// metric mean: metric[t,d] = (sum_{h=0..11} k[t, h*64+d]) / 12  (fp32, h asc)
// ---------------------------------------------------------------------------
__global__ __launch_bounds__(256) void metric_mean_kernel(const float* __restrict__ k32,
                                                          float* __restrict__ metric) {
    int idx = blockIdx.x * 256 + threadIdx.x;     // t*64 + d
    if (idx >= BB * TT * DD) return;
    int t = idx >> 6, d = idx & 63;
    float s = 0.f;
#pragma unroll
    for (int h = 0; h < HH; h++) s += k32[(size_t)t * HID + h * DD + d];
    metric[idx] = s / 12.0f;
}

// ---------------------------------------------------------------------------
// metric normalize: one thread per row, sequential fp32 sum of squares.
// ---------------------------------------------------------------------------
__global__ __launch_bounds__(256) void metric_normalize_kernel(float* __restrict__ metric) {
    int row = blockIdx.x * 256 + threadIdx.x;
    if (row >= BB * TT) return;
    float* p = metric + (size_t)row * DD;
    float ss = 0.f;
#pragma unroll
    for (int d = 0; d < DD; d++) ss += p[d] * p[d];
    float denom = sqrtf(ss) + 1e-6f;
#pragma unroll
    for (int d = 0; d < DD; d++) p[d] = p[d] / denom;
}

// ---------------------------------------------------------------------------
// Partial scores: grid (8 j-splits, 16 i-tiles, B), block 256 (4 waves).
// Lane il caches its a-row (even token 2*(i0+il)) in 16 float4 registers;
// b rows (odd tokens) stream through LDS with wave-uniform broadcast reads.
// Score value = sequential fp32 FMA chain over d ascending (bit-identical to
// the reference-matching chain). Each wave covers 16 j's per 64-chunk, j
// ascending within lane; partial (max, first-argmax) per (i, j-split, wave).
// ---------------------------------------------------------------------------
__global__ __launch_bounds__(256) void tome_scores_part_kernel(const float* __restrict__ metric,
                                                               float* __restrict__ part_max,
                                                               int* __restrict__ part_idx) {
    int b = blockIdx.z;
    int i0 = blockIdx.y * 64;
    int jbase = blockIdx.x * 128;
    int tid = threadIdx.x;
    int il = tid & 63, w = tid >> 6;
    __shared__ float b_lds[64][68];   // 272B rows -> 16B-aligned float4 reads

    const float* arow = metric + ((size_t)b * TT + 2 * (i0 + il)) * DD;
    float4 areg[16];
#pragma unroll
    for (int t = 0; t < 16; t++) areg[t] = ((const float4*)arow)[t];

    float best = -INFINITY;
    int bidx = 0;
    for (int c = 0; c < 2; c++) {
        __syncthreads();
        {
            int r = tid >> 2, cb = (tid & 3) << 4;
            const float* src = metric + ((size_t)b * TT + 2 * (jbase + c * 64 + r) + 1) * DD + cb;
#pragma unroll
            for (int t = 0; t < 4; t++)
                *(float4*)&b_lds[r][cb + 4 * t] = ((const float4*)src)[t];
        }
        __syncthreads();
#pragma unroll
        for (int jj = 0; jj < 16; jj++) {
            int jr = w * 16 + jj;
            float acc = 0.f;
#pragma unroll
            for (int t = 0; t < 16; t++) {
                float4 bv = *(const float4*)&b_lds[jr][t * 4];   // broadcast
                acc += areg[t].x * bv.x;
                acc += areg[t].y * bv.y;
                acc += areg[t].z * bv.z;
                acc += areg[t].w * bv.w;
            }
            int j = jbase + c * 64 + jr;
            if (acc > best) { best = acc; bidx = j; }   // strict > : first max
        }
    }
    int slot = ((b * TH + i0 + il) << 5) + (blockIdx.x << 2) + w;
    part_max[slot] = best;
    part_idx[slot] = bidx;
}

// Combine 32 partials per (b,i): max with lowest-index tie-break == global
// first-occurrence argmax on exact fp32 values.
__global__ __launch_bounds__(1024) void tome_scores_combine_kernel(const float* __restrict__ part_max,
                                                                   const int* __restrict__ part_idx,
                                                                   float* __restrict__ node_max,
                                                                   int* __restrict__ node_idx) {
    int b = blockIdx.x, i = threadIdx.x;
    int base = (b * TH + i) << 5;
    float bv = part_max[base];
    int bi = part_idx[base];
#pragma unroll
    for (int p = 1; p < 32; p++) {
        float v = part_max[base + p];
        int vi = part_idx[base + p];
        if (v > bv || (v == bv && vi < bi)) { bv = v; bi = vi; }
    }
    node_max[b * TH + i] = bv;
    node_idx[b * TH + i] = bi;
}

// ---------------------------------------------------------------------------
// Stable descending argsort via rank counting (fp32 keys, tie -> lower index
// first, matching stable jnp.argsort(-x)). grid B, block 1024.
// ---------------------------------------------------------------------------
__global__ __launch_bounds__(1024) void tome_order_kernel(const float* __restrict__ node_max,
                                                          const int* __restrict__ node_idx,
                                                          int* __restrict__ dst_idx,
                                                          int* __restrict__ src_tok,
                                                          int* __restrict__ unm_tok) {
    __shared__ float vals[TH];
    int b = blockIdx.x;
    int i = threadIdx.x;
    vals[i] = node_max[b * TH + i];
    __syncthreads();
    float v = vals[i];
    int rank = 0;
    for (int j = 0; j < TH; j++) {
        float vj = vals[j];
        rank += (vj > v || (vj == v && j < i)) ? 1 : 0;
    }
    if (rank < RR) {
        src_tok[b * RR + rank] = i;
        dst_idx[b * RR + rank] = node_idx[b * TH + i];
    } else {
        unm_tok[b * UNM + (rank - RR)] = i;
    }
}

__global__ __launch_bounds__(1024) void tome_counts_kernel(const int* __restrict__ dst_idx,
                                                           int* __restrict__ counts) {
    __shared__ int c[TH];
    int b = blockIdx.x;
    int i = threadIdx.x;
    c[i] = 0;
    __syncthreads();
    if (i < RR) atomicAdd(&c[dst_idx[b * RR + i]], 1);
    __syncthreads();
    counts[b * TH + i] = c[i];
}

// ---------------------------------------------------------------------------
// Merge hidden only (merge commutes with affine maps; avg weights sum to 1).
// ---------------------------------------------------------------------------
__global__ __launch_bounds__(192) void merge_base_kernel(const float* __restrict__ in,
                                                         float* __restrict__ out,
                                                         const int* __restrict__ unm_tok) {
    int t = blockIdx.x, b = blockIdx.y;
    int src_row = (t < UNM) ? 2 * unm_tok[b * UNM + t] : 2 * (t - UNM) + 1;
    const float4* src = (const float4*)(in + ((size_t)b * TT + src_row) * HID);
    float4* dst = (float4*)(out + ((size_t)b * T2 + t) * HID);
    dst[threadIdx.x] = src[threadIdx.x];
}

__global__ __launch_bounds__(256) void merge_scatter_kernel(const float* __restrict__ in,
                                                            float* __restrict__ out,
                                                            const int* __restrict__ src_tok,
                                                            const int* __restrict__ dst_idx) {
    int s = blockIdx.x, b = blockIdx.y;
    int srow = 2 * src_tok[b * RR + s];
    int drow = UNM + dst_idx[b * RR + s];
    const float* src = in + ((size_t)b * TT + srow) * HID;
    float* dst = out + ((size_t)b * T2 + drow) * HID;
#pragma unroll
    for (int c = threadIdx.x; c < HID; c += 256) atomicAdd(&dst[c], src[c]);
}

__global__ __launch_bounds__(256) void merge_scale_kernel(float* __restrict__ out,
                                                          const int* __restrict__ counts) {
    int r = blockIdx.x, b = blockIdx.y;
    float inv = 1.0f / (1.0f + (float)counts[b * TH + r]);
    float* dst = out + ((size_t)b * T2 + UNM + r) * HID;
#pragma unroll
    for (int c = threadIdx.x; c < HID; c += 256) dst[c] *= inv;
}

// ---------------------------------------------------------------------------
// MFMA bf16 flash attention. Block = 256 threads = 4 waves; block handles
// 64 q rows of one (b,h); each wave owns 16 q rows. K-chunk = 64 rows.
// ---------------------------------------------------------------------------
__global__ __launch_bounds__(256) void attn_mfma_kernel(float* __restrict__ qm,
                                                        const float* __restrict__ km,
                                                        const float* __restrict__ vm) {
    __shared__ short Ks[64][72];    // K chunk, row-major (j, d), stride 144B
    __shared__ short Vts[64][72];   // V chunk, transposed (d, j)
    __shared__ short Ps[4][16][72]; // per-wave P (16 q rows x 64 j)

    const int b = blockIdx.z, h = blockIdx.y;
    const int tid = threadIdx.x;
    const int w = tid >> 6;          // wave 0..3
    const int lane = tid & 63;
    const int quad = lane >> 4;      // 0..3
    const int l = lane & 15;         // 0..15
    const int q0 = blockIdx.x * 64 + w * 16;   // wave's first q row

    // ---- load Q fragments (A-layout), scaled by 1/8 ----
    bf8v aq0, aq1;
    {
        const float* qp = qm + ((size_t)b * T2 + q0 + l) * HID + h * DD;
        float4 x0 = *(const float4*)(qp + quad * 8);
        float4 x1 = *(const float4*)(qp + quad * 8 + 4);
        float4 x2 = *(const float4*)(qp + 32 + quad * 8);
        float4 x3 = *(const float4*)(qp + 32 + quad * 8 + 4);
        aq0[0] = f2bf(x0.x * SCALEF); aq0[1] = f2bf(x0.y * SCALEF);
        aq0[2] = f2bf(x0.z * SCALEF); aq0[3] = f2bf(x0.w * SCALEF);
        aq0[4] = f2bf(x1.x * SCALEF); aq0[5] = f2bf(x1.y * SCALEF);
        aq0[6] = f2bf(x1.z * SCALEF); aq0[7] = f2bf(x1.w * SCALEF);
        aq1[0] = f2bf(x2.x * SCALEF); aq1[1] = f2bf(x2.y * SCALEF);
        aq1[2] = f2bf(x2.z * SCALEF); aq1[3] = f2bf(x2.w * SCALEF);
        aq1[4] = f2bf(x3.x * SCALEF); aq1[5] = f2bf(x3.y * SCALEF);
        aq1[6] = f2bf(x3.z * SCALEF); aq1[7] = f2bf(x3.w * SCALEF);
    }

    f4v O[4];
#pragma unroll
    for (int t = 0; t < 4; t++) O[t] = (f4v){0.f, 0.f, 0.f, 0.f};
    float mrow[4] = {-INFINITY, -INFINITY, -INFINITY, -INFINITY};
    float lrow[4] = {0.f, 0.f, 0.f, 0.f};

    const int j0s = (tid & 15) << 2;
    const int d0s = (tid >> 4) << 2;

    for (int c0 = 0; c0 < T2; c0 += 64) {
        __syncthreads();
        // ---- stage K (row-major) and V (transposed) as bf16 ----
        {
            float4 kr[4], vr[4];
#pragma unroll
            for (int jj = 0; jj < 4; jj++) {
                size_t base = ((size_t)b * T2 + c0 + j0s + jj) * HID + h * DD + d0s;
                kr[jj] = *(const float4*)(km + base);
                vr[jj] = *(const float4*)(vm + base);
            }
#pragma unroll
            for (int jj = 0; jj < 4; jj++) {
                short4 kk;
                kk.x = f2bf(kr[jj].x); kk.y = f2bf(kr[jj].y);
                kk.z = f2bf(kr[jj].z); kk.w = f2bf(kr[jj].w);
                *(short4*)&Ks[j0s + jj][d0s] = kk;
            }
            {
                short4 t0, t1, t2, t3;
                t0.x = f2bf(vr[0].x); t0.y = f2bf(vr[1].x); t0.z = f2bf(vr[2].x); t0.w = f2bf(vr[3].x);
                t1.x = f2bf(vr[0].y); t1.y = f2bf(vr[1].y); t1.z = f2bf(vr[2].y); t1.w = f2bf(vr[3].y);
                t2.x = f2bf(vr[0].z); t2.y = f2bf(vr[1].z); t2.z = f2bf(vr[2].z); t2.w = f2bf(vr[3].z);
                t3.x = f2bf(vr[0].w); t3.y = f2bf(vr[1].w); t3.z = f2bf(vr[2].w); t3.w = f2bf(vr[3].w);
                *(short4*)&Vts[d0s + 0][j0s] = t0;
                *(short4*)&Vts[d0s + 1][j0s] = t1;
                *(short4*)&Vts[d0s + 2][j0s] = t2;
                *(short4*)&Vts[d0s + 3][j0s] = t3;
            }
        }
        __syncthreads();

        // ---- S = Q K^T (4 j-tiles of 16) ----
        f4v s[4];
#pragma unroll
        for (int t = 0; t < 4; t++) {
            bf8v bk0 = *(const bf8v*)&Ks[t * 16 + l][quad * 8];
            bf8v bk1 = *(const bf8v*)&Ks[t * 16 + l][32 + quad * 8];
            f4v acc = (f4v){0.f, 0.f, 0.f, 0.f};
            acc = __builtin_amdgcn_mfma_f32_16x16x32_bf16(aq0, bk0, acc, 0, 0, 0);
            acc = __builtin_amdgcn_mfma_f32_16x16x32_bf16(aq1, bk1, acc, 0, 0, 0);
            s[t] = acc;
        }

        // ---- online softmax over this chunk ----
        float rmax[4], alpha[4], rsum[4];
#pragma unroll
        for (int r = 0; r < 4; r++) {
            float mx = s[0][r];
            mx = fmaxf(mx, s[1][r]); mx = fmaxf(mx, s[2][r]); mx = fmaxf(mx, s[3][r]);
            rmax[r] = mx;
        }
#pragma unroll
        for (int off = 1; off < 16; off <<= 1) {
#pragma unroll
            for (int r = 0; r < 4; r++) rmax[r] = fmaxf(rmax[r], __shfl_xor(rmax[r], off));
        }
        float p[4][4];
#pragma unroll
        for (int r = 0; r < 4; r++) {
            float mnew = fmaxf(mrow[r], rmax[r]);
            alpha[r] = __expf(mrow[r] - mnew);
            mrow[r] = mnew;
            float ps = 0.f;
#pragma unroll
            for (int t = 0; t < 4; t++) {
                float pv = __expf(s[t][r] - mnew);
                p[t][r] = pv;
                ps += pv;
            }
            rsum[r] = ps;
        }
#pragma unroll
        for (int off = 1; off < 16; off <<= 1) {
#pragma unroll
            for (int r = 0; r < 4; r++) rsum[r] += __shfl_xor(rsum[r], off);
        }
#pragma unroll
        for (int r = 0; r < 4; r++) lrow[r] = lrow[r] * alpha[r] + rsum[r];
#pragma unroll
        for (int t = 0; t < 4; t++)
#pragma unroll
            for (int r = 0; r < 4; r++) O[t][r] *= alpha[r];

        // ---- P to LDS (C-layout -> A-layout round trip) ----
#pragma unroll
        for (int t = 0; t < 4; t++)
#pragma unroll
            for (int r = 0; r < 4; r++)
                Ps[w][quad * 4 + r][t * 16 + l] = f2bf(p[t][r]);

        // ---- O += P V ----
        {
            bf8v ap0 = *(const bf8v*)&Ps[w][l][quad * 8];
            bf8v ap1 = *(const bf8v*)&Ps[w][l][32 + quad * 8];
#pragma unroll
            for (int t = 0; t < 4; t++) {
                bf8v bv0 = *(const bf8v*)&Vts[t * 16 + l][quad * 8];
                bf8v bv1 = *(const bf8v*)&Vts[t * 16 + l][32 + quad * 8];
                O[t] = __builtin_amdgcn_mfma_f32_16x16x32_bf16(ap0, bv0, O[t], 0, 0, 0);
                O[t] = __builtin_amdgcn_mfma_f32_16x16x32_bf16(ap1, bv1, O[t], 0, 0, 0);
            }
        }
    }

    // ---- normalize and write ctx in place of q ----
    float inv[4];
#pragma unroll
    for (int r = 0; r < 4; r++) inv[r] = 1.0f / lrow[r];
#pragma unroll
    for (int r = 0; r < 4; r++) {
        float* op = qm + ((size_t)b * T2 + q0 + quad * 4 + r) * HID + h * DD;
#pragma unroll
        for (int t = 0; t < 4; t++) op[t * 16 + l] = O[t][r] * inv[r];
    }
}

// ---------------------------------------------------------------------------
// LayerNorm in place: grid B*T2 rows, block 256 (each thread 3 cols)
// ---------------------------------------------------------------------------
__global__ __launch_bounds__(256) void ln_kernel(float* __restrict__ out,
                                                 const float* __restrict__ gamma,
                                                 const float* __restrict__ beta) {
    int row = blockIdx.x;
    int tid = threadIdx.x;
    float* p = out + (size_t)row * HID;
    float x[3];
#pragma unroll
    for (int i = 0; i < 3; i++) x[i] = p[tid + i * 256];
    float s = x[0] + x[1] + x[2];
#pragma unroll
    for (int off = 1; off < 64; off <<= 1) s += __shfl_xor(s, off);
    __shared__ float sb[4];
    int wid = tid >> 6;
    if ((tid & 63) == 0) sb[wid] = s;
    __syncthreads();
    float mu = (sb[0] + sb[1] + sb[2] + sb[3]) * (1.0f / HID);
    float vs = 0.f;
#pragma unroll
    for (int i = 0; i < 3; i++) {
        float d = x[i] - mu;
        vs += d * d;
    }
#pragma unroll
    for (int off = 1; off < 64; off <<= 1) vs += __shfl_xor(vs, off);
    __syncthreads();
    if ((tid & 63) == 0) sb[wid] = vs;
    __syncthreads();
    float var = (sb[0] + sb[1] + sb[2] + sb[3]) * (1.0f / HID);
    float inv = rsqrtf(var + 1e-12f);
#pragma unroll
    for (int i = 0; i < 3; i++) {
        int c = tid + i * 256;
        p[c] = (x[i] - mu) * inv * gamma[c] + beta[c];
    }
}

// ---------------------------------------------------------------------------
extern "C" void kernel_launch(void* const* d_in, const int* in_sizes, int n_in,
                              void* d_out, int out_size, void* d_ws, size_t ws_size,
                              hipStream_t stream) {
    const float* hidden = (const float*)d_in[0];
    const float* Wq = (const float*)d_in[1];
    const float* bq = (const float*)d_in[2];
    const float* Wk = (const float*)d_in[3];
    const float* bk = (const float*)d_in[4];
    const float* Wv = (const float*)d_in[5];
    const float* bv = (const float*)d_in[6];
    const float* Wo = (const float*)d_in[7];
    const float* bo = (const float*)d_in[8];
    const float* gamma = (const float*)d_in[9];
    const float* beta = (const float*)d_in[10];

    float* ws = (float*)d_ws;
    const size_t SZ_MERG = (size_t)BB * T2 * HID;   // 4718592 floats
    float* qm = ws;
    float* km = qm + SZ_MERG;
    float* vm = km + SZ_MERG;
    float* k32 = qm;                                 // overlap; dead before step 8
    float* metric = vm + SZ_MERG;                    // B*T*64 fp32
    float* node_max = metric + (size_t)BB * TT * DD; // B*1024 fp32
    int* node_idx = (int*)(node_max + BB * TH);      // B*1024
    int* dst_idx = node_idx + BB * TH;               // B*512
    int* src_tok = dst_idx + BB * RR;                // B*512
    int* unm_tok = src_tok + BB * RR;                // B*512
    int* counts = unm_tok + BB * UNM;                // B*1024
    float* part_max = (float*)(counts + BB * TH);    // B*1024*32 fp32
    int* part_idx = (int*)(part_max + (size_t)BB * TH * 32); // B*1024*32
    float* rm = (float*)d_out;                       // merged residual in d_out

    // 1. full k = hidden @ Wk + bk (fp32, sequential-K chain like BLAS)
    gemm_bias<<<dim3(HID / 64, BB * TT / 64), 256, 0, stream>>>(hidden, Wk, bk, nullptr, k32, BB * TT, HID, HID);

    // 2. metric = head-mean of k (fp32, h ascending, /12)
    metric_mean_kernel<<<(BB * TT * DD + 255) / 256, 256, 0, stream>>>(k32, metric);

    // 3. normalize metric rows (fp32, sequential per row)
    metric_normalize_kernel<<<(BB * TT + 255) / 256, 256, 0, stream>>>(metric);

    // 4. scores -> partial (max, argmax), then combine
    tome_scores_part_kernel<<<dim3(8, 16, BB), 256, 0, stream>>>(metric, part_max, part_idx);
    tome_scores_combine_kernel<<<BB, 1024, 0, stream>>>(part_max, part_idx, node_max, node_idx);

    // 5. stable descending order -> src/unm/dst
    tome_order_kernel<<<BB, 1024, 0, stream>>>(node_max, node_idx, dst_idx, src_tok, unm_tok);

    // 6. counts
    tome_counts_kernel<<<BB, 1024, 0, stream>>>(dst_idx, counts);

    // 7. merge hidden -> rm (residual, in d_out)
    merge_base_kernel<<<dim3(T2, BB), 192, 0, stream>>>(hidden, rm, unm_tok);
    merge_scatter_kernel<<<dim3(RR, BB), 256, 0, stream>>>(hidden, rm, src_tok, dst_idx);
    merge_scale_kernel<<<dim3(TH, BB), 256, 0, stream>>>(rm, counts);

    // 8. QKV projections at T2 (merge commutes with affine maps)
    gemm_bias<<<dim3(HID / 64, BB * T2 / 64), 256, 0, stream>>>(rm, Wq, bq, nullptr, qm, BB * T2, HID, HID);
    gemm_bias<<<dim3(HID / 64, BB * T2 / 64), 256, 0, stream>>>(rm, Wk, bk, nullptr, km, BB * T2, HID, HID);
    gemm_bias<<<dim3(HID / 64, BB * T2 / 64), 256, 0, stream>>>(rm, Wv, bv, nullptr, vm, BB * T2, HID, HID);

    // 9. MFMA flash attention, ctx in-place over qm
    attn_mfma_kernel<<<dim3(T2 / 64, HH, BB), 256, 0, stream>>>(qm, km, vm);

    // 10. out = ctx @ Wo + bo + residual (res aliases C element-wise safely)
    gemm_bias<<<dim3(HID / 64, BB * T2 / 64), 256, 0, stream>>>(qm, Wo, bo, rm, (float*)d_out, BB * T2, HID, HID);

    // 11. LayerNorm in place
    ln_kernel<<<BB * T2, 256, 0, stream>>>((float*)d_out, gamma, beta);
}

// Round 7
// 861.303 us; speedup vs baseline: 4.2716x; 1.1055x over previous
//
#include <hip/hip_runtime.h>
#include <math.h>

#define BB 4
#define TT 2048
#define HH 12
#define DD 64
#define HID 768
#define RR 512
#define T2 1536
#define TH 1024   // T/2
#define UNM 512   // TH - R
#define SCALEF 0.125f

typedef short bf8v __attribute__((ext_vector_type(8)));
typedef float f4v  __attribute__((ext_vector_type(4)));

// float -> bf16 round-to-nearest-even
__device__ inline short f2bf(float f) {
    unsigned u = __float_as_uint(f);
    u += 0x7fffu + ((u >> 16) & 1u);
    return (short)(u >> 16);
}

// ---------------------------------------------------------------------------
// fp32 tiled GEMM: C = A[M,K] @ W[K,N] + bias (+ res in mode 0 if res!=null)
// 64x64 tile, BK=16, 256 threads, 4x4/thread, sequential-K fp32 chain
// (reference-faithful for the index path).
// mode 0: fp32 out [M,N];  mode 1: bf16 out [M,N];
// mode 2: bf16 out transposed per head: dst[((b*HH+h)*DD+d)*T2 + t]
//         (requires M = BB*T2, N = HID; tiles never cross b or h).
// ---------------------------------------------------------------------------
__global__ __launch_bounds__(256) void gemm_bias(const float* __restrict__ A,
                                                 const float* __restrict__ Wt,
                                                 const float* __restrict__ bias,
                                                 const float* __restrict__ res,
                                                 void* __restrict__ Cout,
                                                 int M, int N, int K, int mode) {
    __shared__ float As[16][68];   // transposed A tile, padded
    __shared__ float Bs[16][64];
    int tid = threadIdx.x;
    int n0 = blockIdx.x * 64, m0 = blockIdx.y * 64;
    int tx = tid & 15, ty = tid >> 4;
    int la_m = tid >> 2, la_k = (tid & 3) << 2;
    int lb_k = tid >> 4, lb_n = (tid & 15) << 2;
    float acc[4][4] = {};
    for (int k0 = 0; k0 < K; k0 += 16) {
        float4 av = *(const float4*)(A + (size_t)(m0 + la_m) * K + k0 + la_k);
        float4 bv = *(const float4*)(Wt + (size_t)(k0 + lb_k) * N + n0 + lb_n);
        As[la_k + 0][la_m] = av.x; As[la_k + 1][la_m] = av.y;
        As[la_k + 2][la_m] = av.z; As[la_k + 3][la_m] = av.w;
        *(float4*)&Bs[lb_k][lb_n] = bv;
        __syncthreads();
#pragma unroll
        for (int kk = 0; kk < 16; kk++) {
            float4 a = *(const float4*)&As[kk][ty << 2];
            float4 b = *(const float4*)&Bs[kk][tx << 2];
            float ar[4] = {a.x, a.y, a.z, a.w};
            float br[4] = {b.x, b.y, b.z, b.w};
#pragma unroll
            for (int i = 0; i < 4; i++)
#pragma unroll
                for (int j = 0; j < 4; j++) acc[i][j] += ar[i] * br[j];
        }
        __syncthreads();
    }
    float4 bvv = *(const float4*)(bias + n0 + (tx << 2));
    float bb4[4] = {bvv.x, bvv.y, bvv.z, bvv.w};
    if (mode == 0) {
        float* C = (float*)Cout;
#pragma unroll
        for (int i = 0; i < 4; i++) {
            int m = m0 + (ty << 2) + i;
            float4 v;
            v.x = acc[i][0] + bb4[0]; v.y = acc[i][1] + bb4[1];
            v.z = acc[i][2] + bb4[2]; v.w = acc[i][3] + bb4[3];
            if (res) {
                float4 r = *(const float4*)(res + (size_t)m * N + n0 + (tx << 2));
                v.x += r.x; v.y += r.y; v.z += r.z; v.w += r.w;
            }
            *(float4*)(C + (size_t)m * N + n0 + (tx << 2)) = v;
        }
    } else if (mode == 1) {
        short* C = (short*)Cout;
#pragma unroll
        for (int i = 0; i < 4; i++) {
            int m = m0 + (ty << 2) + i;
            short4 sv;
            sv.x = f2bf(acc[i][0] + bb4[0]); sv.y = f2bf(acc[i][1] + bb4[1]);
            sv.z = f2bf(acc[i][2] + bb4[2]); sv.w = f2bf(acc[i][3] + bb4[3]);
            *(short4*)(C + (size_t)m * N + n0 + (tx << 2)) = sv;
        }
    } else {
        short* C = (short*)Cout;
        int bb = m0 / T2;
        int t0 = (m0 % T2) + (ty << 2);
        int h = n0 >> 6;
        int dbase = (n0 & 63) + (tx << 2);
#pragma unroll
        for (int j = 0; j < 4; j++) {
            int d = dbase + j;
            short4 sv;
            sv.x = f2bf(acc[0][j] + bb4[j]); sv.y = f2bf(acc[1][j] + bb4[j]);
            sv.z = f2bf(acc[2][j] + bb4[j]); sv.w = f2bf(acc[3][j] + bb4[j]);
            *(short4*)(C + (((size_t)bb * HH + h) * DD + d) * T2 + t0) = sv;
        }
    }
}

// ---------------------------------------------------------------------------
// metric mean: metric[t,d] = (sum_{h=0..11} k[t, h*64+d]) / 12  (fp32, h asc)
// ---------------------------------------------------------------------------
__global__ __launch_bounds__(256) void metric_mean_kernel(const float* __restrict__ k32,
                                                          float* __restrict__ metric) {
    int idx = blockIdx.x * 256 + threadIdx.x;     // t*64 + d
    if (idx >= BB * TT * DD) return;
    int t = idx >> 6, d = idx & 63;
    float s = 0.f;
#pragma unroll
    for (int h = 0; h < HH; h++) s += k32[(size_t)t * HID + h * DD + d];
    metric[idx] = s / 12.0f;
}

// ---------------------------------------------------------------------------
// metric normalize: one thread per row, sequential fp32 sum of squares.
// ---------------------------------------------------------------------------
__global__ __launch_bounds__(256) void metric_normalize_kernel(float* __restrict__ metric) {
    int row = blockIdx.x * 256 + threadIdx.x;
    if (row >= BB * TT) return;
    float* p = metric + (size_t)row * DD;
    float ss = 0.f;
#pragma unroll
    for (int d = 0; d < DD; d++) ss += p[d] * p[d];
    float denom = sqrtf(ss) + 1e-6f;
#pragma unroll
    for (int d = 0; d < DD; d++) p[d] = p[d] / denom;
}

// ---------------------------------------------------------------------------
// Partial scores: grid (8 j-splits, 16 i-tiles, B), block 256 (4 waves).
// ---------------------------------------------------------------------------
__global__ __launch_bounds__(256) void tome_scores_part_kernel(const float* __restrict__ metric,
                                                               float* __restrict__ part_max,
                                                               int* __restrict__ part_idx) {
    int b = blockIdx.z;
    int i0 = blockIdx.y * 64;
    int jbase = blockIdx.x * 128;
    int tid = threadIdx.x;
    int il = tid & 63, w = tid >> 6;
    __shared__ float b_lds[64][68];   // 272B rows -> 16B-aligned float4 reads

    const float* arow = metric + ((size_t)b * TT + 2 * (i0 + il)) * DD;
    float4 areg[16];
#pragma unroll
    for (int t = 0; t < 16; t++) areg[t] = ((const float4*)arow)[t];

    float best = -INFINITY;
    int bidx = 0;
    for (int c = 0; c < 2; c++) {
        __syncthreads();
        {
            int r = tid >> 2, cb = (tid & 3) << 4;
            const float* src = metric + ((size_t)b * TT + 2 * (jbase + c * 64 + r) + 1) * DD + cb;
#pragma unroll
            for (int t = 0; t < 4; t++)
                *(float4*)&b_lds[r][cb + 4 * t] = ((const float4*)src)[t];
        }
        __syncthreads();
#pragma unroll
        for (int jj = 0; jj < 16; jj++) {
            int jr = w * 16 + jj;
            float acc = 0.f;
#pragma unroll
            for (int t = 0; t < 16; t++) {
                float4 bv = *(const float4*)&b_lds[jr][t * 4];   // broadcast
                acc += areg[t].x * bv.x;
                acc += areg[t].y * bv.y;
                acc += areg[t].z * bv.z;
                acc += areg[t].w * bv.w;
            }
            int j = jbase + c * 64 + jr;
            if (acc > best) { best = acc; bidx = j; }   // strict > : first max
        }
    }
    int slot = ((b * TH + i0 + il) << 5) + (blockIdx.x << 2) + w;
    part_max[slot] = best;
    part_idx[slot] = bidx;
}

// Combine 32 partials per (b,i).
__global__ __launch_bounds__(1024) void tome_scores_combine_kernel(const float* __restrict__ part_max,
                                                                   const int* __restrict__ part_idx,
                                                                   float* __restrict__ node_max,
                                                                   int* __restrict__ node_idx) {
    int b = blockIdx.x, i = threadIdx.x;
    int base = (b * TH + i) << 5;
    float bv = part_max[base];
    int bi = part_idx[base];
#pragma unroll
    for (int p = 1; p < 32; p++) {
        float v = part_max[base + p];
        int vi = part_idx[base + p];
        if (v > bv || (v == bv && vi < bi)) { bv = v; bi = vi; }
    }
    node_max[b * TH + i] = bv;
    node_idx[b * TH + i] = bi;
}

// ---------------------------------------------------------------------------
// Stable descending argsort via rank counting. grid B, block 1024.
// ---------------------------------------------------------------------------
__global__ __launch_bounds__(1024) void tome_order_kernel(const float* __restrict__ node_max,
                                                          const int* __restrict__ node_idx,
                                                          int* __restrict__ dst_idx,
                                                          int* __restrict__ src_tok,
                                                          int* __restrict__ unm_tok) {
    __shared__ float vals[TH];
    int b = blockIdx.x;
    int i = threadIdx.x;
    vals[i] = node_max[b * TH + i];
    __syncthreads();
    float v = vals[i];
    int rank = 0;
    for (int j = 0; j < TH; j++) {
        float vj = vals[j];
        rank += (vj > v || (vj == v && j < i)) ? 1 : 0;
    }
    if (rank < RR) {
        src_tok[b * RR + rank] = i;
        dst_idx[b * RR + rank] = node_idx[b * TH + i];
    } else {
        unm_tok[b * UNM + (rank - RR)] = i;
    }
}

__global__ __launch_bounds__(1024) void tome_counts_kernel(const int* __restrict__ dst_idx,
                                                           int* __restrict__ counts) {
    __shared__ int c[TH];
    int b = blockIdx.x;
    int i = threadIdx.x;
    c[i] = 0;
    __syncthreads();
    if (i < RR) atomicAdd(&c[dst_idx[b * RR + i]], 1);
    __syncthreads();
    counts[b * TH + i] = c[i];
}

// ---------------------------------------------------------------------------
// Merge hidden only (merge commutes with affine maps; avg weights sum to 1).
// ---------------------------------------------------------------------------
__global__ __launch_bounds__(192) void merge_base_kernel(const float* __restrict__ in,
                                                         float* __restrict__ out,
                                                         const int* __restrict__ unm_tok) {
    int t = blockIdx.x, b = blockIdx.y;
    int src_row = (t < UNM) ? 2 * unm_tok[b * UNM + t] : 2 * (t - UNM) + 1;
    const float4* src = (const float4*)(in + ((size_t)b * TT + src_row) * HID);
    float4* dst = (float4*)(out + ((size_t)b * T2 + t) * HID);
    dst[threadIdx.x] = src[threadIdx.x];
}

__global__ __launch_bounds__(256) void merge_scatter_kernel(const float* __restrict__ in,
                                                            float* __restrict__ out,
                                                            const int* __restrict__ src_tok,
                                                            const int* __restrict__ dst_idx) {
    int s = blockIdx.x, b = blockIdx.y;
    int srow = 2 * src_tok[b * RR + s];
    int drow = UNM + dst_idx[b * RR + s];
    const float* src = in + ((size_t)b * TT + srow) * HID;
    float* dst = out + ((size_t)b * T2 + drow) * HID;
#pragma unroll
    for (int c = threadIdx.x; c < HID; c += 256) atomicAdd(&dst[c], src[c]);
}

__global__ __launch_bounds__(256) void merge_scale_kernel(float* __restrict__ out,
                                                          const int* __restrict__ counts) {
    int r = blockIdx.x, b = blockIdx.y;
    float inv = 1.0f / (1.0f + (float)counts[b * TH + r]);
    float* dst = out + ((size_t)b * T2 + UNM + r) * HID;
#pragma unroll
    for (int c = threadIdx.x; c < HID; c += 256) dst[c] *= inv;
}

// ---------------------------------------------------------------------------
// MFMA bf16 flash attention, transposed form (S^T / O^T).
// Block = 4 waves, 64 q rows of one (b,h); wave owns 16 q rows; K-chunk 64.
// A = K (from bf16 kmb), B = Q^T (regs); A = V^T (from pre-transposed vtb),
// B = P^T. C-layout: n = lane&15 = qrow, m = quad*4+reg = j (or d).
// P^T stores are short4 (8B), staging is pure 16B copies (no converts, no
// in-LDS transpose). In-place: each wave writes only its own (rows, head).
// ---------------------------------------------------------------------------
__global__ __launch_bounds__(256) void attn_mfma_kernel(float* __restrict__ qm,
                                                        const short* __restrict__ kmb,
                                                        const short* __restrict__ vtb) {
    __shared__ short Ks[64][72];    // K chunk row-major (j, d)
    __shared__ short Vts[64][72];   // V^T chunk (d, j)
    __shared__ short Pt[4][16][72]; // per-wave P^T as (qrow, j)

    const int b = blockIdx.z, h = blockIdx.y;
    const int tid = threadIdx.x;
    const int w = tid >> 6;
    const int lane = tid & 63;
    const int quad = lane >> 4;
    const int l = lane & 15;
    const int q0 = blockIdx.x * 64 + w * 16;

    // ---- Q as B-frag: lane l holds Q[q0+l][quad*8+i], scaled by 1/8 ----
    bf8v bq0, bq1;
    {
        const float* qp = qm + ((size_t)b * T2 + q0 + l) * HID + h * DD;
        float4 x0 = *(const float4*)(qp + quad * 8);
        float4 x1 = *(const float4*)(qp + quad * 8 + 4);
        float4 x2 = *(const float4*)(qp + 32 + quad * 8);
        float4 x3 = *(const float4*)(qp + 32 + quad * 8 + 4);
        bq0[0] = f2bf(x0.x * SCALEF); bq0[1] = f2bf(x0.y * SCALEF);
        bq0[2] = f2bf(x0.z * SCALEF); bq0[3] = f2bf(x0.w * SCALEF);
        bq0[4] = f2bf(x1.x * SCALEF); bq0[5] = f2bf(x1.y * SCALEF);
        bq0[6] = f2bf(x1.z * SCALEF); bq0[7] = f2bf(x1.w * SCALEF);
        bq1[0] = f2bf(x2.x * SCALEF); bq1[1] = f2bf(x2.y * SCALEF);
        bq1[2] = f2bf(x2.z * SCALEF); bq1[3] = f2bf(x2.w * SCALEF);
        bq1[4] = f2bf(x3.x * SCALEF); bq1[5] = f2bf(x3.y * SCALEF);
        bq1[6] = f2bf(x3.z * SCALEF); bq1[7] = f2bf(x3.w * SCALEF);
    }

    f4v O[4];
#pragma unroll
    for (int t = 0; t < 4; t++) O[t] = (f4v){0.f, 0.f, 0.f, 0.f};
    float m_st = -INFINITY, l_st = 0.f;

    const int rstg = tid >> 2;          // 0..63
    const int cstg = (tid & 3) << 4;    // 0,16,32,48 shorts
    const short* kbase = kmb + (size_t)b * T2 * HID + h * DD;
    const short* vbase = vtb + (((size_t)b * HH + h) * DD + rstg) * T2;

    for (int c0 = 0; c0 < T2; c0 += 64) {
        __syncthreads();
        {
            const short* ksrc = kbase + (size_t)(c0 + rstg) * HID + cstg;
            *(bf8v*)&Ks[rstg][cstg]     = *(const bf8v*)ksrc;
            *(bf8v*)&Ks[rstg][cstg + 8] = *(const bf8v*)(ksrc + 8);
            const short* vsrc = vbase + c0 + cstg;
            *(bf8v*)&Vts[rstg][cstg]     = *(const bf8v*)vsrc;
            *(bf8v*)&Vts[rstg][cstg + 8] = *(const bf8v*)(vsrc + 8);
        }
        __syncthreads();

        // ---- S^T = K Q^T: s[t] holds j = c0 + t*16 + quad*4 + r, qrow = l ----
        f4v s[4];
#pragma unroll
        for (int t = 0; t < 4; t++) {
            bf8v ak0 = *(const bf8v*)&Ks[t * 16 + l][quad * 8];
            bf8v ak1 = *(const bf8v*)&Ks[t * 16 + l][32 + quad * 8];
            f4v acc = (f4v){0.f, 0.f, 0.f, 0.f};
            acc = __builtin_amdgcn_mfma_f32_16x16x32_bf16(ak0, bq0, acc, 0, 0, 0);
            acc = __builtin_amdgcn_mfma_f32_16x16x32_bf16(ak1, bq1, acc, 0, 0, 0);
            s[t] = acc;
        }

        // ---- online softmax (row = lane's qrow; reduce over quads) ----
        float mx = s[0][0];
#pragma unroll
        for (int t = 0; t < 4; t++)
#pragma unroll
            for (int r = 0; r < 4; r++) mx = fmaxf(mx, s[t][r]);
        mx = fmaxf(mx, __shfl_xor(mx, 16));
        mx = fmaxf(mx, __shfl_xor(mx, 32));
        float mnew = fmaxf(m_st, mx);
        float alpha = __expf(m_st - mnew);
        float p[4][4];
        float sum = 0.f;
#pragma unroll
        for (int t = 0; t < 4; t++)
#pragma unroll
            for (int r = 0; r < 4; r++) {
                float pv = __expf(s[t][r] - mnew);
                p[t][r] = pv;
                sum += pv;
            }
        sum += __shfl_xor(sum, 16);
        sum += __shfl_xor(sum, 32);
        l_st = l_st * alpha + sum;
        m_st = mnew;
#pragma unroll
        for (int t = 0; t < 4; t++) {
            O[t][0] *= alpha; O[t][1] *= alpha; O[t][2] *= alpha; O[t][3] *= alpha;
        }

        // ---- P^T to LDS: row = qrow (l), cols j; 4 consecutive j per store ----
#pragma unroll
        for (int t = 0; t < 4; t++) {
            short4 pv;
            pv.x = f2bf(p[t][0]); pv.y = f2bf(p[t][1]);
            pv.z = f2bf(p[t][2]); pv.w = f2bf(p[t][3]);
            *(short4*)&Pt[w][l][t * 16 + quad * 4] = pv;
        }

        // ---- O^T += V^T P^T ----
        {
            bf8v bp0 = *(const bf8v*)&Pt[w][l][quad * 8];
            bf8v bp1 = *(const bf8v*)&Pt[w][l][32 + quad * 8];
#pragma unroll
            for (int t = 0; t < 4; t++) {
                bf8v av0 = *(const bf8v*)&Vts[t * 16 + l][quad * 8];
                bf8v av1 = *(const bf8v*)&Vts[t * 16 + l][32 + quad * 8];
                O[t] = __builtin_amdgcn_mfma_f32_16x16x32_bf16(av0, bp0, O[t], 0, 0, 0);
                O[t] = __builtin_amdgcn_mfma_f32_16x16x32_bf16(av1, bp1, O[t], 0, 0, 0);
            }
        }
    }

    // ---- normalize, write ctx in place (row q0+l, d = t*16+quad*4+r) ----
    float inv = 1.0f / l_st;
    float* op = qm + ((size_t)b * T2 + q0 + l) * HID + h * DD;
#pragma unroll
    for (int t = 0; t < 4; t++) {
        float4 ov;
        ov.x = O[t][0] * inv; ov.y = O[t][1] * inv;
        ov.z = O[t][2] * inv; ov.w = O[t][3] * inv;
        *(float4*)(op + t * 16 + quad * 4) = ov;
    }
}

// ---------------------------------------------------------------------------
// LayerNorm in place: grid B*T2 rows, block 256 (each thread 3 cols)
// ---------------------------------------------------------------------------
__global__ __launch_bounds__(256) void ln_kernel(float* __restrict__ out,
                                                 const float* __restrict__ gamma,
                                                 const float* __restrict__ beta) {
    int row = blockIdx.x;
    int tid = threadIdx.x;
    float* p = out + (size_t)row * HID;
    float x[3];
#pragma unroll
    for (int i = 0; i < 3; i++) x[i] = p[tid + i * 256];
    float s = x[0] + x[1] + x[2];
#pragma unroll
    for (int off = 1; off < 64; off <<= 1) s += __shfl_xor(s, off);
    __shared__ float sb[4];
    int wid = tid >> 6;
    if ((tid & 63) == 0) sb[wid] = s;
    __syncthreads();
    float mu = (sb[0] + sb[1] + sb[2] + sb[3]) * (1.0f / HID);
    float vs = 0.f;
#pragma unroll
    for (int i = 0; i < 3; i++) {
        float d = x[i] - mu;
        vs += d * d;
    }
#pragma unroll
    for (int off = 1; off < 64; off <<= 1) vs += __shfl_xor(vs, off);
    __syncthreads();
    if ((tid & 63) == 0) sb[wid] = vs;
    __syncthreads();
    float var = (sb[0] + sb[1] + sb[2] + sb[3]) * (1.0f / HID);
    float inv = rsqrtf(var + 1e-12f);
#pragma unroll
    for (int i = 0; i < 3; i++) {
        int c = tid + i * 256;
        p[c] = (x[i] - mu) * inv * gamma[c] + beta[c];
    }
}

// ---------------------------------------------------------------------------
extern "C" void kernel_launch(void* const* d_in, const int* in_sizes, int n_in,
                              void* d_out, int out_size, void* d_ws, size_t ws_size,
                              hipStream_t stream) {
    const float* hidden = (const float*)d_in[0];
    const float* Wq = (const float*)d_in[1];
    const float* bq = (const float*)d_in[2];
    const float* Wk = (const float*)d_in[3];
    const float* bk = (const float*)d_in[4];
    const float* Wv = (const float*)d_in[5];
    const float* bv = (const float*)d_in[6];
    const float* Wo = (const float*)d_in[7];
    const float* bo = (const float*)d_in[8];
    const float* gamma = (const float*)d_in[9];
    const float* beta = (const float*)d_in[10];

    float* ws = (float*)d_ws;
    const size_t SZ_MERG = (size_t)BB * T2 * HID;   // 4718592 elements
    float* qm = ws;                                  // fp32 ctx/q
    short* kmb = (short*)(qm + SZ_MERG);             // bf16 k, [B*T2, HID]
    short* vtb = kmb + SZ_MERG;                      // bf16 v^T, [B,H,D,T2]
    float* k32 = qm;                                 // full fp32 k (25.2MB):
                                                     // spans qm+part of kmb;
                                                     // dead before step 8
    float* metric = (float*)(vtb + SZ_MERG);         // B*T*64 fp32
    float* node_max = metric + (size_t)BB * TT * DD; // B*1024 fp32
    int* node_idx = (int*)(node_max + BB * TH);      // B*1024
    int* dst_idx = node_idx + BB * TH;               // B*512
    int* src_tok = dst_idx + BB * RR;                // B*512
    int* unm_tok = src_tok + BB * RR;                // B*512
    int* counts = unm_tok + BB * UNM;                // B*1024
    float* part_max = (float*)(counts + BB * TH);    // B*1024*32 fp32
    int* part_idx = (int*)(part_max + (size_t)BB * TH * 32); // B*1024*32
    float* rm = (float*)d_out;                       // merged residual in d_out

    // 1. full k = hidden @ Wk + bk (fp32, sequential-K chain like BLAS)
    gemm_bias<<<dim3(HID / 64, BB * TT / 64), 256, 0, stream>>>(hidden, Wk, bk, nullptr, k32, BB * TT, HID, HID, 0);

    // 2. metric = head-mean of k (fp32, h ascending, /12)
    metric_mean_kernel<<<(BB * TT * DD + 255) / 256, 256, 0, stream>>>(k32, metric);

    // 3. normalize metric rows (fp32, sequential per row)
    metric_normalize_kernel<<<(BB * TT + 255) / 256, 256, 0, stream>>>(metric);

    // 4. scores -> partial (max, argmax), then combine
    tome_scores_part_kernel<<<dim3(8, 16, BB), 256, 0, stream>>>(metric, part_max, part_idx);
    tome_scores_combine_kernel<<<BB, 1024, 0, stream>>>(part_max, part_idx, node_max, node_idx);

    // 5. stable descending order -> src/unm/dst
    tome_order_kernel<<<BB, 1024, 0, stream>>>(node_max, node_idx, dst_idx, src_tok, unm_tok);

    // 6. counts
    tome_counts_kernel<<<BB, 1024, 0, stream>>>(dst_idx, counts);

    // 7. merge hidden -> rm (residual, in d_out)
    merge_base_kernel<<<dim3(T2, BB), 192, 0, stream>>>(hidden, rm, unm_tok);
    merge_scatter_kernel<<<dim3(RR, BB), 256, 0, stream>>>(hidden, rm, src_tok, dst_idx);
    merge_scale_kernel<<<dim3(TH, BB), 256, 0, stream>>>(rm, counts);

    // 8. QKV projections at T2; k as bf16, v as bf16 transposed-per-head
    gemm_bias<<<dim3(HID / 64, BB * T2 / 64), 256, 0, stream>>>(rm, Wq, bq, nullptr, qm, BB * T2, HID, HID, 0);
    gemm_bias<<<dim3(HID / 64, BB * T2 / 64), 256, 0, stream>>>(rm, Wk, bk, nullptr, kmb, BB * T2, HID, HID, 1);
    gemm_bias<<<dim3(HID / 64, BB * T2 / 64), 256, 0, stream>>>(rm, Wv, bv, nullptr, vtb, BB * T2, HID, HID, 2);

    // 9. MFMA flash attention (transposed form), ctx in-place over qm
    attn_mfma_kernel<<<dim3(T2 / 64, HH, BB), 256, 0, stream>>>(qm, kmb, vtb);

    // 10. out = ctx @ Wo + bo + residual (res aliases C element-wise safely)
    gemm_bias<<<dim3(HID / 64, BB * T2 / 64), 256, 0, stream>>>(qm, Wo, bo, rm, d_out, BB * T2, HID, HID, 0);

    // 11. LayerNorm in place
    ln_kernel<<<BB * T2, 256, 0, stream>>>((float*)d_out, gamma, beta);
}

// Round 8
// 543.509 us; speedup vs baseline: 6.7692x; 1.5847x over previous
//
#include <hip/hip_runtime.h>
#include <math.h>

#define BB 4
#define TT 2048
#define HH 12
#define DD 64
#define HID 768
#define RR 512
#define T2 1536
#define TH 1024   // T/2
#define UNM 512   // TH - R
#define SCALEF 0.125f

typedef short bf8v __attribute__((ext_vector_type(8)));
typedef float f4v  __attribute__((ext_vector_type(4)));

// float -> bf16 round-to-nearest-even
__device__ inline short f2bf(float f) {
    unsigned u = __float_as_uint(f);
    u += 0x7fffu + ((u >> 16) & 1u);
    return (short)(u >> 16);
}

// ---------------------------------------------------------------------------
// fp32 tiled GEMM (index path ONLY): C = A@W + bias. Sequential-K fp32 chain,
// reference-faithful. 64x64 tile, BK=16, 4x4/thread.
// ---------------------------------------------------------------------------
__global__ __launch_bounds__(256) void gemm_bias(const float* __restrict__ A,
                                                 const float* __restrict__ Wt,
                                                 const float* __restrict__ bias,
                                                 float* __restrict__ C,
                                                 int M, int N, int K) {
    __shared__ float As[16][68];
    __shared__ float Bs[16][64];
    int tid = threadIdx.x;
    int n0 = blockIdx.x * 64, m0 = blockIdx.y * 64;
    int tx = tid & 15, ty = tid >> 4;
    int la_m = tid >> 2, la_k = (tid & 3) << 2;
    int lb_k = tid >> 4, lb_n = (tid & 15) << 2;
    float acc[4][4] = {};
    for (int k0 = 0; k0 < K; k0 += 16) {
        float4 av = *(const float4*)(A + (size_t)(m0 + la_m) * K + k0 + la_k);
        float4 bv = *(const float4*)(Wt + (size_t)(k0 + lb_k) * N + n0 + lb_n);
        As[la_k + 0][la_m] = av.x; As[la_k + 1][la_m] = av.y;
        As[la_k + 2][la_m] = av.z; As[la_k + 3][la_m] = av.w;
        *(float4*)&Bs[lb_k][lb_n] = bv;
        __syncthreads();
#pragma unroll
        for (int kk = 0; kk < 16; kk++) {
            float4 a = *(const float4*)&As[kk][ty << 2];
            float4 b = *(const float4*)&Bs[kk][tx << 2];
            float ar[4] = {a.x, a.y, a.z, a.w};
            float br[4] = {b.x, b.y, b.z, b.w};
#pragma unroll
            for (int i = 0; i < 4; i++)
#pragma unroll
                for (int j = 0; j < 4; j++) acc[i][j] += ar[i] * br[j];
        }
        __syncthreads();
    }
    float4 bvv = *(const float4*)(bias + n0 + (tx << 2));
#pragma unroll
    for (int i = 0; i < 4; i++) {
        int m = m0 + (ty << 2) + i;
        float4 v;
        v.x = acc[i][0] + bvv.x; v.y = acc[i][1] + bvv.y;
        v.z = acc[i][2] + bvv.z; v.w = acc[i][3] + bvv.w;
        *(float4*)(C + (size_t)m * N + n0 + (tx << 2)) = v;
    }
}

// ---------------------------------------------------------------------------
// Weight transpose + bf16 convert: Wt_b[n][k] = bf16(W[k][n]). 4 matrices.
// ---------------------------------------------------------------------------
struct WPtrs {
    const float* w[4];
    short* wt[4];
};

__global__ __launch_bounds__(256) void transpose_w_kernel(WPtrs p) {
    __shared__ short tile[64][65];
    const float* W = p.w[blockIdx.z];
    short* Wt = p.wt[blockIdx.z];
    int k0 = blockIdx.x * 64, n0 = blockIdx.y * 64;
    int tid = threadIdx.x;
#pragma unroll
    for (int i = 0; i < 16; i++) {
        int idx = tid + i * 256;
        int r = idx >> 6, c = idx & 63;
        tile[c][r] = f2bf(W[(size_t)(k0 + r) * HID + n0 + c]);
    }
    __syncthreads();
#pragma unroll
    for (int i = 0; i < 16; i++) {
        int idx = tid + i * 256;
        int r = idx >> 6, c = idx & 63;
        Wt[(size_t)(n0 + r) * HID + k0 + c] = tile[r][c];
    }
}

// fp32 -> bf16 elementwise (float4 granularity)
__global__ __launch_bounds__(256) void f32_to_bf16_kernel(const float* __restrict__ in,
                                                          short* __restrict__ out, int n4) {
    int i = blockIdx.x * 256 + threadIdx.x;
    if (i >= n4) return;
    float4 v = ((const float4*)in)[i];
    short4 s;
    s.x = f2bf(v.x); s.y = f2bf(v.y); s.z = f2bf(v.z); s.w = f2bf(v.w);
    ((short4*)out)[i] = s;
}

// ---------------------------------------------------------------------------
// bf16 MFMA GEMM: C = A[M,768] @ B[768,768] + bias, B given transposed bf16
// (Bt[n][k]). 128x128 tile, BK=32, 4 waves (2x2 of 64x64), 16 MFMA/wave/iter.
// fp32 accumulate. Epilogue modes:
//  0: fp32 out + res (res==C aliasing safe)   [out-proj]
//  1: bf16 out row-major                      [k]
//  2: bf16 out transposed per head [B,H,D,T2] [v]
//  3: bf16 out row-major, scaled by 0.125     [q]
// ---------------------------------------------------------------------------
__global__ __launch_bounds__(256) void gemm_mfma(const short* __restrict__ A,
                                                 const short* __restrict__ Bt,
                                                 const float* __restrict__ bias,
                                                 const float* __restrict__ res,
                                                 void* __restrict__ Cout,
                                                 int M, int mode) {
    __shared__ short As[128][40];   // stride 40 shorts (80B): 16B-aligned, ~2-way banks
    __shared__ short Bs[128][40];
    int tid = threadIdx.x;
    int m0 = blockIdx.y * 128, n0 = blockIdx.x * 128;
    int w = tid >> 6, lane = tid & 63, quad = lane >> 4, l = lane & 15;
    int wm = (w & 1) << 6, wn = (w >> 1) << 6;

    f4v acc[4][4];
#pragma unroll
    for (int i = 0; i < 4; i++)
#pragma unroll
        for (int j = 0; j < 4; j++) acc[i][j] = (f4v){0.f, 0.f, 0.f, 0.f};

    int srow = tid >> 1, sseg = (tid & 1) << 4;
    const short* ag = A + (size_t)(m0 + srow) * HID + sseg;
    const short* bg = Bt + (size_t)(n0 + srow) * HID + sseg;

    for (int k0 = 0; k0 < HID; k0 += 32) {
        __syncthreads();
        *(bf8v*)&As[srow][sseg]     = *(const bf8v*)(ag + k0);
        *(bf8v*)&As[srow][sseg + 8] = *(const bf8v*)(ag + k0 + 8);
        *(bf8v*)&Bs[srow][sseg]     = *(const bf8v*)(bg + k0);
        *(bf8v*)&Bs[srow][sseg + 8] = *(const bf8v*)(bg + k0 + 8);
        __syncthreads();
        bf8v af[4], bfv[4];
#pragma unroll
        for (int mt = 0; mt < 4; mt++) af[mt] = *(const bf8v*)&As[wm + mt * 16 + l][quad * 8];
#pragma unroll
        for (int nt = 0; nt < 4; nt++) bfv[nt] = *(const bf8v*)&Bs[wn + nt * 16 + l][quad * 8];
#pragma unroll
        for (int mt = 0; mt < 4; mt++)
#pragma unroll
            for (int nt = 0; nt < 4; nt++)
                acc[mt][nt] = __builtin_amdgcn_mfma_f32_16x16x32_bf16(af[mt], bfv[nt], acc[mt][nt], 0, 0, 0);
    }

    float bia[4];
#pragma unroll
    for (int nt = 0; nt < 4; nt++) bia[nt] = bias[n0 + wn + nt * 16 + l];

    if (mode == 0) {
        float* C = (float*)Cout;
#pragma unroll
        for (int mt = 0; mt < 4; mt++)
#pragma unroll
            for (int r = 0; r < 4; r++) {
                int m = m0 + wm + mt * 16 + quad * 4 + r;
#pragma unroll
                for (int nt = 0; nt < 4; nt++) {
                    int n = n0 + wn + nt * 16 + l;
                    C[(size_t)m * HID + n] = acc[mt][nt][r] + bia[nt] + res[(size_t)m * HID + n];
                }
            }
    } else if (mode == 1 || mode == 3) {
        short* C = (short*)Cout;
        float sc = (mode == 3) ? SCALEF : 1.0f;
#pragma unroll
        for (int mt = 0; mt < 4; mt++)
#pragma unroll
            for (int r = 0; r < 4; r++) {
                int m = m0 + wm + mt * 16 + quad * 4 + r;
#pragma unroll
                for (int nt = 0; nt < 4; nt++) {
                    int n = n0 + wn + nt * 16 + l;
                    C[(size_t)m * HID + n] = f2bf((acc[mt][nt][r] + bia[nt]) * sc);
                }
            }
    } else {
        // v transposed per head: out[((b*HH+h)*DD+d)*T2 + t]
        short* C = (short*)Cout;
#pragma unroll
        for (int nt = 0; nt < 4; nt++) {
            int n = n0 + wn + nt * 16 + l;
            int h = n >> 6, d = n & 63;
#pragma unroll
            for (int mt = 0; mt < 4; mt++) {
                int m = m0 + wm + mt * 16 + quad * 4;
                int b = m / T2, t = m % T2;
                short4 sv;
                sv.x = f2bf(acc[mt][nt][0] + bia[nt]);
                sv.y = f2bf(acc[mt][nt][1] + bia[nt]);
                sv.z = f2bf(acc[mt][nt][2] + bia[nt]);
                sv.w = f2bf(acc[mt][nt][3] + bia[nt]);
                *(short4*)(C + (((size_t)b * HH + h) * DD + d) * T2 + t) = sv;
            }
        }
    }
}

// ---------------------------------------------------------------------------
// metric mean: metric[t,d] = (sum_{h} k[t, h*64+d]) / 12  (fp32, h ascending)
// ---------------------------------------------------------------------------
__global__ __launch_bounds__(256) void metric_mean_kernel(const float* __restrict__ k32,
                                                          float* __restrict__ metric) {
    int idx = blockIdx.x * 256 + threadIdx.x;
    if (idx >= BB * TT * DD) return;
    int t = idx >> 6, d = idx & 63;
    float s = 0.f;
#pragma unroll
    for (int h = 0; h < HH; h++) s += k32[(size_t)t * HID + h * DD + d];
    metric[idx] = s / 12.0f;
}

__global__ __launch_bounds__(256) void metric_normalize_kernel(float* __restrict__ metric) {
    int row = blockIdx.x * 256 + threadIdx.x;
    if (row >= BB * TT) return;
    float* p = metric + (size_t)row * DD;
    float ss = 0.f;
#pragma unroll
    for (int d = 0; d < DD; d++) ss += p[d] * p[d];
    float denom = sqrtf(ss) + 1e-6f;
#pragma unroll
    for (int d = 0; d < DD; d++) p[d] = p[d] / denom;
}

// ---------------------------------------------------------------------------
// Partial scores: grid (8 j-splits, 16 i-tiles, B), block 256 (4 waves).
// ---------------------------------------------------------------------------
__global__ __launch_bounds__(256) void tome_scores_part_kernel(const float* __restrict__ metric,
                                                               float* __restrict__ part_max,
                                                               int* __restrict__ part_idx) {
    int b = blockIdx.z;
    int i0 = blockIdx.y * 64;
    int jbase = blockIdx.x * 128;
    int tid = threadIdx.x;
    int il = tid & 63, w = tid >> 6;
    __shared__ float b_lds[64][68];

    const float* arow = metric + ((size_t)b * TT + 2 * (i0 + il)) * DD;
    float4 areg[16];
#pragma unroll
    for (int t = 0; t < 16; t++) areg[t] = ((const float4*)arow)[t];

    float best = -INFINITY;
    int bidx = 0;
    for (int c = 0; c < 2; c++) {
        __syncthreads();
        {
            int r = tid >> 2, cb = (tid & 3) << 4;
            const float* src = metric + ((size_t)b * TT + 2 * (jbase + c * 64 + r) + 1) * DD + cb;
#pragma unroll
            for (int t = 0; t < 4; t++)
                *(float4*)&b_lds[r][cb + 4 * t] = ((const float4*)src)[t];
        }
        __syncthreads();
#pragma unroll
        for (int jj = 0; jj < 16; jj++) {
            int jr = w * 16 + jj;
            float acc = 0.f;
#pragma unroll
            for (int t = 0; t < 16; t++) {
                float4 bv = *(const float4*)&b_lds[jr][t * 4];
                acc += areg[t].x * bv.x;
                acc += areg[t].y * bv.y;
                acc += areg[t].z * bv.z;
                acc += areg[t].w * bv.w;
            }
            int j = jbase + c * 64 + jr;
            if (acc > best) { best = acc; bidx = j; }
        }
    }
    int slot = ((b * TH + i0 + il) << 5) + (blockIdx.x << 2) + w;
    part_max[slot] = best;
    part_idx[slot] = bidx;
}

__global__ __launch_bounds__(1024) void tome_scores_combine_kernel(const float* __restrict__ part_max,
                                                                   const int* __restrict__ part_idx,
                                                                   float* __restrict__ node_max,
                                                                   int* __restrict__ node_idx) {
    int b = blockIdx.x, i = threadIdx.x;
    int base = (b * TH + i) << 5;
    float bv = part_max[base];
    int bi = part_idx[base];
#pragma unroll
    for (int p = 1; p < 32; p++) {
        float v = part_max[base + p];
        int vi = part_idx[base + p];
        if (v > bv || (v == bv && vi < bi)) { bv = v; bi = vi; }
    }
    node_max[b * TH + i] = bv;
    node_idx[b * TH + i] = bi;
}

// ---------------------------------------------------------------------------
// Stable descending argsort via rank counting. grid B, block 1024.
// ---------------------------------------------------------------------------
__global__ __launch_bounds__(1024) void tome_order_kernel(const float* __restrict__ node_max,
                                                          const int* __restrict__ node_idx,
                                                          int* __restrict__ dst_idx,
                                                          int* __restrict__ src_tok,
                                                          int* __restrict__ unm_tok) {
    __shared__ float vals[TH];
    int b = blockIdx.x;
    int i = threadIdx.x;
    vals[i] = node_max[b * TH + i];
    __syncthreads();
    float v = vals[i];
    int rank = 0;
    for (int j = 0; j < TH; j++) {
        float vj = vals[j];
        rank += (vj > v || (vj == v && j < i)) ? 1 : 0;
    }
    if (rank < RR) {
        src_tok[b * RR + rank] = i;
        dst_idx[b * RR + rank] = node_idx[b * TH + i];
    } else {
        unm_tok[b * UNM + (rank - RR)] = i;
    }
}

__global__ __launch_bounds__(1024) void tome_counts_kernel(const int* __restrict__ dst_idx,
                                                           int* __restrict__ counts) {
    __shared__ int c[TH];
    int b = blockIdx.x;
    int i = threadIdx.x;
    c[i] = 0;
    __syncthreads();
    if (i < RR) atomicAdd(&c[dst_idx[b * RR + i]], 1);
    __syncthreads();
    counts[b * TH + i] = c[i];
}

// ---------------------------------------------------------------------------
// Merge hidden only (merge commutes with affine maps; avg weights sum to 1).
// ---------------------------------------------------------------------------
__global__ __launch_bounds__(192) void merge_base_kernel(const float* __restrict__ in,
                                                         float* __restrict__ out,
                                                         const int* __restrict__ unm_tok) {
    int t = blockIdx.x, b = blockIdx.y;
    int src_row = (t < UNM) ? 2 * unm_tok[b * UNM + t] : 2 * (t - UNM) + 1;
    const float4* src = (const float4*)(in + ((size_t)b * TT + src_row) * HID);
    float4* dst = (float4*)(out + ((size_t)b * T2 + t) * HID);
    dst[threadIdx.x] = src[threadIdx.x];
}

__global__ __launch_bounds__(256) void merge_scatter_kernel(const float* __restrict__ in,
                                                            float* __restrict__ out,
                                                            const int* __restrict__ src_tok,
                                                            const int* __restrict__ dst_idx) {
    int s = blockIdx.x, b = blockIdx.y;
    int srow = 2 * src_tok[b * RR + s];
    int drow = UNM + dst_idx[b * RR + s];
    const float* src = in + ((size_t)b * TT + srow) * HID;
    float* dst = out + ((size_t)b * T2 + drow) * HID;
#pragma unroll
    for (int c = threadIdx.x; c < HID; c += 256) atomicAdd(&dst[c], src[c]);
}

__global__ __launch_bounds__(256) void merge_scale_kernel(float* __restrict__ out,
                                                          const int* __restrict__ counts) {
    int r = blockIdx.x, b = blockIdx.y;
    float inv = 1.0f / (1.0f + (float)counts[b * TH + r]);
    float* dst = out + ((size_t)b * T2 + UNM + r) * HID;
#pragma unroll
    for (int c = threadIdx.x; c < HID; c += 256) dst[c] *= inv;
}

// ---------------------------------------------------------------------------
// MFMA bf16 flash attention, transposed form (S^T / O^T). All-bf16 I/O:
// q pre-scaled bf16 in qmb (ctx written back bf16 in place), k bf16 row-major,
// v bf16 pre-transposed per head.
// ---------------------------------------------------------------------------
__global__ __launch_bounds__(256) void attn_mfma_kernel(short* __restrict__ qmb,
                                                        const short* __restrict__ kmb,
                                                        const short* __restrict__ vtb) {
    __shared__ short Ks[64][72];
    __shared__ short Vts[64][72];
    __shared__ short Pt[4][16][72];

    const int b = blockIdx.z, h = blockIdx.y;
    const int tid = threadIdx.x;
    const int w = tid >> 6;
    const int lane = tid & 63;
    const int quad = lane >> 4;
    const int l = lane & 15;
    const int q0 = blockIdx.x * 64 + w * 16;

    // ---- Q as B-frag (already scaled by 1/8, bf16) ----
    short* qp = qmb + ((size_t)b * T2 + q0 + l) * HID + h * DD;
    bf8v bq0 = *(const bf8v*)(qp + quad * 8);
    bf8v bq1 = *(const bf8v*)(qp + 32 + quad * 8);

    f4v O[4];
#pragma unroll
    for (int t = 0; t < 4; t++) O[t] = (f4v){0.f, 0.f, 0.f, 0.f};
    float m_st = -INFINITY, l_st = 0.f;

    const int rstg = tid >> 2;
    const int cstg = (tid & 3) << 4;
    const short* kbase = kmb + (size_t)b * T2 * HID + h * DD;
    const short* vbase = vtb + (((size_t)b * HH + h) * DD + rstg) * T2;

    for (int c0 = 0; c0 < T2; c0 += 64) {
        __syncthreads();
        {
            const short* ksrc = kbase + (size_t)(c0 + rstg) * HID + cstg;
            *(bf8v*)&Ks[rstg][cstg]     = *(const bf8v*)ksrc;
            *(bf8v*)&Ks[rstg][cstg + 8] = *(const bf8v*)(ksrc + 8);
            const short* vsrc = vbase + c0 + cstg;
            *(bf8v*)&Vts[rstg][cstg]     = *(const bf8v*)vsrc;
            *(bf8v*)&Vts[rstg][cstg + 8] = *(const bf8v*)(vsrc + 8);
        }
        __syncthreads();

        f4v s[4];
#pragma unroll
        for (int t = 0; t < 4; t++) {
            bf8v ak0 = *(const bf8v*)&Ks[t * 16 + l][quad * 8];
            bf8v ak1 = *(const bf8v*)&Ks[t * 16 + l][32 + quad * 8];
            f4v acc = (f4v){0.f, 0.f, 0.f, 0.f};
            acc = __builtin_amdgcn_mfma_f32_16x16x32_bf16(ak0, bq0, acc, 0, 0, 0);
            acc = __builtin_amdgcn_mfma_f32_16x16x32_bf16(ak1, bq1, acc, 0, 0, 0);
            s[t] = acc;
        }

        float mx = s[0][0];
#pragma unroll
        for (int t = 0; t < 4; t++)
#pragma unroll
            for (int r = 0; r < 4; r++) mx = fmaxf(mx, s[t][r]);
        mx = fmaxf(mx, __shfl_xor(mx, 16));
        mx = fmaxf(mx, __shfl_xor(mx, 32));
        float mnew = fmaxf(m_st, mx);
        float alpha = __expf(m_st - mnew);
        float p[4][4];
        float sum = 0.f;
#pragma unroll
        for (int t = 0; t < 4; t++)
#pragma unroll
            for (int r = 0; r < 4; r++) {
                float pv = __expf(s[t][r] - mnew);
                p[t][r] = pv;
                sum += pv;
            }
        sum += __shfl_xor(sum, 16);
        sum += __shfl_xor(sum, 32);
        l_st = l_st * alpha + sum;
        m_st = mnew;
#pragma unroll
        for (int t = 0; t < 4; t++) {
            O[t][0] *= alpha; O[t][1] *= alpha; O[t][2] *= alpha; O[t][3] *= alpha;
        }

#pragma unroll
        for (int t = 0; t < 4; t++) {
            short4 pv;
            pv.x = f2bf(p[t][0]); pv.y = f2bf(p[t][1]);
            pv.z = f2bf(p[t][2]); pv.w = f2bf(p[t][3]);
            *(short4*)&Pt[w][l][t * 16 + quad * 4] = pv;
        }

        {
            bf8v bp0 = *(const bf8v*)&Pt[w][l][quad * 8];
            bf8v bp1 = *(const bf8v*)&Pt[w][l][32 + quad * 8];
#pragma unroll
            for (int t = 0; t < 4; t++) {
                bf8v av0 = *(const bf8v*)&Vts[t * 16 + l][quad * 8];
                bf8v av1 = *(const bf8v*)&Vts[t * 16 + l][32 + quad * 8];
                O[t] = __builtin_amdgcn_mfma_f32_16x16x32_bf16(av0, bp0, O[t], 0, 0, 0);
                O[t] = __builtin_amdgcn_mfma_f32_16x16x32_bf16(av1, bp1, O[t], 0, 0, 0);
            }
        }
    }

    // ---- normalize, write ctx (bf16) in place ----
    float inv = 1.0f / l_st;
#pragma unroll
    for (int t = 0; t < 4; t++) {
        short4 ov;
        ov.x = f2bf(O[t][0] * inv); ov.y = f2bf(O[t][1] * inv);
        ov.z = f2bf(O[t][2] * inv); ov.w = f2bf(O[t][3] * inv);
        *(short4*)(qp + t * 16 + quad * 4) = ov;
    }
}

// ---------------------------------------------------------------------------
// LayerNorm in place: grid B*T2 rows, block 256 (each thread 3 cols)
// ---------------------------------------------------------------------------
__global__ __launch_bounds__(256) void ln_kernel(float* __restrict__ out,
                                                 const float* __restrict__ gamma,
                                                 const float* __restrict__ beta) {
    int row = blockIdx.x;
    int tid = threadIdx.x;
    float* p = out + (size_t)row * HID;
    float x[3];
#pragma unroll
    for (int i = 0; i < 3; i++) x[i] = p[tid + i * 256];
    float s = x[0] + x[1] + x[2];
#pragma unroll
    for (int off = 1; off < 64; off <<= 1) s += __shfl_xor(s, off);
    __shared__ float sb[4];
    int wid = tid >> 6;
    if ((tid & 63) == 0) sb[wid] = s;
    __syncthreads();
    float mu = (sb[0] + sb[1] + sb[2] + sb[3]) * (1.0f / HID);
    float vs = 0.f;
#pragma unroll
    for (int i = 0; i < 3; i++) {
        float d = x[i] - mu;
        vs += d * d;
    }
#pragma unroll
    for (int off = 1; off < 64; off <<= 1) vs += __shfl_xor(vs, off);
    __syncthreads();
    if ((tid & 63) == 0) sb[wid] = vs;
    __syncthreads();
    float var = (sb[0] + sb[1] + sb[2] + sb[3]) * (1.0f / HID);
    float inv = rsqrtf(var + 1e-12f);
#pragma unroll
    for (int i = 0; i < 3; i++) {
        int c = tid + i * 256;
        p[c] = (x[i] - mu) * inv * gamma[c] + beta[c];
    }
}

// ---------------------------------------------------------------------------
extern "C" void kernel_launch(void* const* d_in, const int* in_sizes, int n_in,
                              void* d_out, int out_size, void* d_ws, size_t ws_size,
                              hipStream_t stream) {
    const float* hidden = (const float*)d_in[0];
    const float* Wq = (const float*)d_in[1];
    const float* bq = (const float*)d_in[2];
    const float* Wk = (const float*)d_in[3];
    const float* bk = (const float*)d_in[4];
    const float* Wv = (const float*)d_in[5];
    const float* bv = (const float*)d_in[6];
    const float* Wo = (const float*)d_in[7];
    const float* bo = (const float*)d_in[8];
    const float* gamma = (const float*)d_in[9];
    const float* beta = (const float*)d_in[10];

    const size_t SZ_MERG = (size_t)BB * T2 * HID;    // 4718592 elements
    short* qmb = (short*)d_ws;                        // bf16 q (scaled) / ctx
    short* kmb = qmb + SZ_MERG;                       // bf16 k row-major
    short* vtb = kmb + SZ_MERG;                       // bf16 v^T [B,H,D,T2]
    short* rmb = vtb + SZ_MERG;                       // bf16 merged hidden
    short* wqb = rmb + SZ_MERG;                       // bf16 W^T [N,K] x4
    short* wkb = wqb + HID * HID;
    short* wvb = wkb + HID * HID;
    short* wob = wvb + HID * HID;
    float* k32 = (float*)d_ws;                        // fp32 k (25.2MB) overlaps
                                                      // qmb..vtb; dead by step 8
    float* metric = (float*)(wob + HID * HID);        // B*T*64 fp32
    float* node_max = metric + (size_t)BB * TT * DD;
    int* node_idx = (int*)(node_max + BB * TH);
    int* dst_idx = node_idx + BB * TH;
    int* src_tok = dst_idx + BB * RR;
    int* unm_tok = src_tok + BB * RR;
    int* counts = unm_tok + BB * UNM;
    float* part_max = (float*)(counts + BB * TH);
    int* part_idx = (int*)(part_max + (size_t)BB * TH * 32);
    float* rm = (float*)d_out;                        // merged residual in d_out

    // 0. weight transpose+bf16 (independent of everything; note wqb.. region
    //    does NOT overlap k32)
    WPtrs wp;
    wp.w[0] = Wq; wp.w[1] = Wk; wp.w[2] = Wv; wp.w[3] = Wo;
    wp.wt[0] = wqb; wp.wt[1] = wkb; wp.wt[2] = wvb; wp.wt[3] = wob;
    transpose_w_kernel<<<dim3(HID / 64, HID / 64, 4), 256, 0, stream>>>(wp);

    // 1. full k = hidden @ Wk + bk (fp32, sequential-K chain — index path)
    gemm_bias<<<dim3(HID / 64, BB * TT / 64), 256, 0, stream>>>(hidden, Wk, bk, k32, BB * TT, HID, HID);

    // 2-3. metric = head-mean of k, then row-normalize (fp32)
    metric_mean_kernel<<<(BB * TT * DD + 255) / 256, 256, 0, stream>>>(k32, metric);
    metric_normalize_kernel<<<(BB * TT + 255) / 256, 256, 0, stream>>>(metric);

    // 4. scores -> partial (max, argmax), then combine
    tome_scores_part_kernel<<<dim3(8, 16, BB), 256, 0, stream>>>(metric, part_max, part_idx);
    tome_scores_combine_kernel<<<BB, 1024, 0, stream>>>(part_max, part_idx, node_max, node_idx);

    // 5-6. stable order + counts
    tome_order_kernel<<<BB, 1024, 0, stream>>>(node_max, node_idx, dst_idx, src_tok, unm_tok);
    tome_counts_kernel<<<BB, 1024, 0, stream>>>(dst_idx, counts);

    // 7. merge hidden -> rm (residual, in d_out); then bf16 copy
    merge_base_kernel<<<dim3(T2, BB), 192, 0, stream>>>(hidden, rm, unm_tok);
    merge_scatter_kernel<<<dim3(RR, BB), 256, 0, stream>>>(hidden, rm, src_tok, dst_idx);
    merge_scale_kernel<<<dim3(TH, BB), 256, 0, stream>>>(rm, counts);
    f32_to_bf16_kernel<<<(int)((SZ_MERG / 4 + 255) / 256), 256, 0, stream>>>(rm, rmb, (int)(SZ_MERG / 4));

    // 8. QKV projections via bf16 MFMA (q scaled+bf16, k bf16, v bf16-T)
    gemm_mfma<<<dim3(HID / 128, BB * T2 / 128), 256, 0, stream>>>(rmb, wqb, bq, nullptr, qmb, BB * T2, 3);
    gemm_mfma<<<dim3(HID / 128, BB * T2 / 128), 256, 0, stream>>>(rmb, wkb, bk, nullptr, kmb, BB * T2, 1);
    gemm_mfma<<<dim3(HID / 128, BB * T2 / 128), 256, 0, stream>>>(rmb, wvb, bv, nullptr, vtb, BB * T2, 2);

    // 9. MFMA flash attention (all-bf16 I/O), ctx in place of q
    attn_mfma_kernel<<<dim3(T2 / 64, HH, BB), 256, 0, stream>>>(qmb, kmb, vtb);

    // 10. out = ctx @ Wo + bo + residual (fp32 epilogue; res==C alias safe)
    gemm_mfma<<<dim3(HID / 128, BB * T2 / 128), 256, 0, stream>>>(qmb, wob, bo, rm, d_out, BB * T2, 0);

    // 11. LayerNorm in place
    ln_kernel<<<BB * T2, 256, 0, stream>>>((float*)d_out, gamma, beta);
}